// Round 5
// baseline (214.021 us; speedup 1.0000x reference)
//
#include <hip/hip_runtime.h>

typedef unsigned short u16;
typedef unsigned int u32;
typedef __attribute__((ext_vector_type(8))) __bf16 bf16x8;
typedef __attribute__((ext_vector_type(4))) float f32x4;
typedef __attribute__((ext_vector_type(4))) unsigned short u16x4;
typedef __attribute__((ext_vector_type(2))) unsigned int u32x2;

#define SEQ 2048
#define DM 1024
#define NH 16
#define DH 64
// M = BATCH*SEQ = 4096, N = 1024, K = 1024 for all GEMMs

__device__ __forceinline__ float fexp2(float x) {
  return __builtin_amdgcn_exp2f(x); // raw v_exp_f32 (2^x)
}

__device__ __forceinline__ unsigned short f2bf(float f) {
  unsigned u = __builtin_bit_cast(unsigned, f);
  u += 0x7fffu + ((u >> 16) & 1u);
  return (unsigned short)(u >> 16);
}

__device__ __forceinline__ u32 cvtpk(float lo, float hi) { // {bf16(lo), bf16(hi)}
  u32 r;
  asm("v_cvt_pk_bf16_f32 %0, %1, %2" : "=v"(r) : "v"(lo), "v"(hi));
  return r;
}

__device__ __forceinline__ void gload_lds16(const u16* g, u16* l) {
  __builtin_amdgcn_global_load_lds(
      (const __attribute__((address_space(1))) u16*)g,
      (__attribute__((address_space(3))) u16*)l, 16, 0, 0);
}

// ---------- convert x fp32 -> bf16 ----------
__global__ __launch_bounds__(256) void cvt_kernel(const float* __restrict__ in,
                                                  u16* __restrict__ out, int n4) {
  int id = blockIdx.x * 256 + threadIdx.x;
  if (id >= n4) return;
  float4 v = ((const float4*)in)[id];
  u16x4 o = { f2bf(v.x), f2bf(v.y), f2bf(v.z), f2bf(v.w) };
  ((u16x4*)out)[id] = o;
}

// ---------- transpose + convert weights (all 4 in one launch, z selects) ----
__global__ __launch_bounds__(256) void wtrans_kernel(const float* __restrict__ W0,
                                                     const float* __restrict__ W1,
                                                     const float* __restrict__ W2,
                                                     const float* __restrict__ W3,
                                                     u16* __restrict__ WtBase) {
  const float* W = (blockIdx.z == 0) ? W0 : (blockIdx.z == 1) ? W1
                 : (blockIdx.z == 2) ? W2 : W3;
  u16* Wt = WtBase + ((size_t)blockIdx.z << 20);
  __shared__ float tile[32][33];
  int tx = threadIdx.x & 31, ty = threadIdx.x >> 5; // 32 x 8
  int k0 = blockIdx.y * 32, n0 = blockIdx.x * 32;
#pragma unroll
  for (int j = 0; j < 32; j += 8)
    tile[ty + j][tx] = W[(size_t)(k0 + ty + j) * DM + n0 + tx];
  __syncthreads();
#pragma unroll
  for (int j = 0; j < 32; j += 8)
    Wt[(size_t)(n0 + ty + j) * DM + k0 + tx] = f2bf(tile[tx][ty + j]);
}

// ---------- GEMM: C = A(bf16 [4096,1024]) @ Wt^T + bias ----------
// modes: 0=Q  -> [B,H,S,DH] bf16, scaled by 0.125*log2(e) (softmax in exp2)
//        1=K  -> [B,H,S,DH] bf16
//        2=V  -> [B,H,DH,S] bf16 (transposed for PV A-fragments)
//        3=O  -> [4096,1024] fp32 (final output)
template <int BM, int BN>
__global__ __launch_bounds__(256) void gemm_kernel(
    const u16* __restrict__ A, const u16* __restrict__ WtBase,
    const float* __restrict__ b0, const float* __restrict__ b1,
    const float* __restrict__ b2,
    void* __restrict__ O0, void* __restrict__ O1, void* __restrict__ O2,
    int modeBase) {
  constexpr int MR = BM / 32, NR = BN / 32; // fragments per wave (2x2 wave grid)
  const int Kd = 1024, Nd = 1024;
  const int mode = modeBase + blockIdx.z;
  const u16* Bt = WtBase + ((size_t)blockIdx.z << 20);
  const float* bias = (blockIdx.z == 0) ? b0 : (blockIdx.z == 1) ? b1 : b2;
  void* Out = (blockIdx.z == 0) ? O0 : (blockIdx.z == 1) ? O1 : O2;

  __shared__ u16 As[2][BM * 32];
  __shared__ u16 Bs[2][BN * 32];
  const int tid = threadIdx.x;
  const int lane = tid & 63, w = tid >> 6;
  const int lrow = lane & 15, u = lane >> 4;
  const int wr = w >> 1, wc = w & 1;
  const int brow = blockIdx.y * BM, bcol = blockIdx.x * BN;

  f32x4 acc[MR][NR] = {};

  const int srow = tid >> 2;        // 0..63 per issue
  const int scol = (tid & 3) * 8;
  const u16* aP = A + (size_t)(brow + srow) * Kd + scol;
  const u16* bP = Bt + (size_t)(bcol + srow) * Kd + scol;

  auto stage = [&](int kt, int buf) {
#pragma unroll
    for (int i = 0; i < BM / 64; ++i)
      gload_lds16(aP + (size_t)i * 64 * Kd + kt, As[buf] + i * 2048 + w * 512);
#pragma unroll
    for (int i = 0; i < BN / 64; ++i)
      gload_lds16(bP + (size_t)i * 64 * Kd + kt, Bs[buf] + i * 2048 + w * 512);
  };

  stage(0, 0);
  __syncthreads();

  for (int it = 0; it < 32; ++it) {
    const int cur = it & 1;
    if (it + 1 < 32) stage((it + 1) * 32, cur ^ 1); // prefetch overlaps compute
    bf16x8 af[MR], bfr[NR];
#pragma unroll
    for (int m = 0; m < MR; ++m)
      af[m] = *(const bf16x8*)(As[cur] + (wr * (BM / 2) + m * 16 + lrow) * 32 + u * 8);
#pragma unroll
    for (int n = 0; n < NR; ++n)
      bfr[n] = *(const bf16x8*)(Bs[cur] + (wc * (BN / 2) + n * 16 + lrow) * 32 + u * 8);
#pragma unroll
    for (int m = 0; m < MR; ++m)
#pragma unroll
      for (int n = 0; n < NR; ++n)
        acc[m][n] = __builtin_amdgcn_mfma_f32_16x16x32_bf16(af[m], bfr[n], acc[m][n], 0, 0, 0);
    __syncthreads();
  }

  const int r0 = brow + wr * (BM / 2) + u * 4; // + m*16 + i
  const int c0 = bcol + wc * (BN / 2) + lrow;  // + n*16
#pragma unroll
  for (int m = 0; m < MR; ++m) {
#pragma unroll
    for (int n = 0; n < NR; ++n) {
      const int col = c0 + n * 16;
      const float bv = bias[col];
      if (mode == 3) {
        float* O = (float*)Out;
#pragma unroll
        for (int i = 0; i < 4; ++i) {
          int row = r0 + m * 16 + i;
          O[(size_t)row * Nd + col] = acc[m][n][i] + bv;
        }
      } else if (mode == 2) {
        // V transposed: Vt[((b*16+h)*64+dh)*2048 + s], 4 consecutive s per thread
        const int rowb = r0 + m * 16;
        const int b = rowb >> 11, s = rowb & 2047;
        const int h = col >> 6, dh = col & 63;
        u16x4 pk;
#pragma unroll
        for (int i = 0; i < 4; ++i) pk[i] = f2bf(acc[m][n][i] + bv);
        u16* O = (u16*)Out;
        *(u16x4*)(O + ((size_t)((b * NH + h) * DH + dh) * SEQ + s)) = pk;
      } else {
        const float sc = (mode == 0) ? 0.1803368801111204f : 1.0f; // 0.125*log2e
        u16* O = (u16*)Out;
#pragma unroll
        for (int i = 0; i < 4; ++i) {
          int row = r0 + m * 16 + i;
          int b = row >> 11, s = row & 2047;
          int h = col >> 6, dh = col & 63;
          O[((size_t)(b * NH + h) * SEQ + s) * DH + dh] = f2bf((acc[m][n][i] + bv) * sc);
        }
      }
    }
  }
}

// ---------- causal flash attention, v4 (fused A/B streams) ----------
// grid: (16 qpairs, 32 bh). Block = 256 threads = 4 waves.
// Swapped layout: mfma(K,Q) -> lane owns ONE q-row (q=lane&15), k in-lane.
// K/V fragments loaded ONCE per iter, shared by both streams (halves DS reads).
// Softmax: in-lane tree + 2 shuffles + defer-max; P packed via v_cvt_pk_bf16_f32.
__device__ __forceinline__ void softmax_update(f32x4 (&s)[4], f32x4 (&hacc)[4],
                                               float& m_i, float& l_i) {
  float pg0 = fmaxf(fmaxf(s[0][0], s[0][1]), fmaxf(s[0][2], s[0][3]));
  float pg1 = fmaxf(fmaxf(s[1][0], s[1][1]), fmaxf(s[1][2], s[1][3]));
  float pg2 = fmaxf(fmaxf(s[2][0], s[2][1]), fmaxf(s[2][2], s[2][3]));
  float pg3 = fmaxf(fmaxf(s[3][0], s[3][1]), fmaxf(s[3][2], s[3][3]));
  float pmax = fmaxf(fmaxf(pg0, pg1), fmaxf(pg2, pg3));
  pmax = fmaxf(pmax, __shfl_xor(pmax, 16));
  pmax = fmaxf(pmax, __shfl_xor(pmax, 32));
  if (__any(pmax > m_i + 8.0f)) { // defer-max: P bounded by 2^8, bf16-safe
    const float mnew = fmaxf(m_i, pmax);
    const float scl = fexp2(m_i - mnew);
    l_i *= scl;
#pragma unroll
    for (int g = 0; g < 4; ++g) hacc[g] *= scl;
    m_i = mnew;
  }
  float rs = 0.f;
#pragma unroll
  for (int g = 0; g < 4; ++g)
#pragma unroll
    for (int i = 0; i < 4; ++i) {
      const float p = fexp2(s[g][i] - m_i);
      s[g][i] = p;
      rs += p;
    }
  rs += __shfl_xor(rs, 16);
  rs += __shfl_xor(rs, 32);
  l_i += rs;
}

__device__ __forceinline__ void write_p(u16* ps, const f32x4 (&s)[4], int lrow, int u) {
#pragma unroll
  for (int g = 0; g < 4; ++g) {
    u32x2 pw = { cvtpk(s[g][0], s[g][1]), cvtpk(s[g][2], s[g][3]) };
    *(u32x2*)(ps + ((lrow * 128 + ((g * 32 + u * 8) ^ ((lrow & 7) << 4))) >> 1)) = pw;
  }
}

__global__ __launch_bounds__(256, 2) void attn_kernel(const u16* __restrict__ Qb,
                                                      const u16* __restrict__ Kb,
                                                      const u16* __restrict__ Vt,
                                                      u16* __restrict__ Hh) {
  const int px = blockIdx.x, bh = blockIdx.y;
  const int qtA = px, qtB = 31 - px;
  const int tid = threadIdx.x, lane = tid & 63, w = tid >> 6;
  const int lrow = lane & 15, u = lane >> 4;

  const u16* Qp = Qb + (size_t)bh * SEQ * DH;
  const u16* Kp = Kb + (size_t)bh * SEQ * DH;
  const u16* Vp = Vt + (size_t)bh * DH * SEQ;

  __shared__ u16 KV[2][2][4096];   // [buf][K=0/V=1][64x64], swizzled
  __shared__ u16 Ps[4][2][1024];   // [wave][stream][16x64], swizzled

  const int q0A = qtA * 64 + w * 16, q0B = qtB * 64 + w * 16;
  bf16x8 qfA[2], qfB[2];
#pragma unroll
  for (int ks = 0; ks < 2; ++ks) {
    qfA[ks] = *(const bf16x8*)(Qp + (size_t)(q0A + lrow) * DH + ks * 32 + u * 8);
    qfB[ks] = *(const bf16x8*)(Qp + (size_t)(q0B + lrow) * DH + ks * 32 + u * 8);
  }

  float mA = -1e30f, lA = 0.f, mB = -1e30f, lB = 0.f;
  f32x4 haccA[4], haccB[4];
#pragma unroll
  for (int g = 0; g < 4; ++g) {
    haccA[g] = (f32x4){0.f, 0.f, 0.f, 0.f};
    haccB[g] = (f32x4){0.f, 0.f, 0.f, 0.f};
  }

  // cooperative tile stage: 256 thr x 16B x 2 issues per 8KB tile
  auto stage = [&](int kt, int buf) {
#pragma unroll
    for (int i = 0; i < 2; ++i) {
      const int p = i * 4096 + tid * 16;          // linear phys byte in tile
      const int row = p >> 7;                     // 128B rows
      const int c16 = ((p >> 4) & 7) ^ (row & 7); // pre-swizzled source col (16B units)
      gload_lds16(Kp + (size_t)(kt * 64 + row) * 64 + c16 * 8, &KV[buf][0][p >> 1]);
      gload_lds16(Vp + (size_t)row * 2048 + (size_t)kt * 64 + c16 * 8, &KV[buf][1][p >> 1]);
    }
  };

  stage(0, 0);
  __syncthreads();

  const int wq = w * 16 + lrow;
  const int nkt = qtB + 1;
  for (int kt = 0; kt < nkt; ++kt) {
    const int cur = kt & 1;
    if (kt + 1 < nkt) stage(kt + 1, cur ^ 1); // prefetch overlaps compute
    const u16* bufK = KV[cur][0];
    const u16* bufV = KV[cur][1];
    const bool doA = (kt <= qtA);

    // --- K fragments, shared by both streams ---
    bf16x8 kf[2][4];
#pragma unroll
    for (int ks = 0; ks < 2; ++ks) {
      const int c = ks * 64 + u * 16;
#pragma unroll
      for (int g = 0; g < 4; ++g) {
        const int r = g * 16 + lrow;
        kf[ks][g] = *(const bf16x8*)(bufK + ((r * 128 + (c ^ ((r & 7) << 4))) >> 1));
      }
    }
    // --- QK^T both streams (16 independent MFMAs) ---
    f32x4 sA[4] = {}, sB[4] = {};
#pragma unroll
    for (int ks = 0; ks < 2; ++ks)
#pragma unroll
      for (int g = 0; g < 4; ++g)
        sB[g] = __builtin_amdgcn_mfma_f32_16x16x32_bf16(kf[ks][g], qfB[ks], sB[g], 0, 0, 0);
    if (doA) {
#pragma unroll
      for (int ks = 0; ks < 2; ++ks)
#pragma unroll
        for (int g = 0; g < 4; ++g)
          sA[g] = __builtin_amdgcn_mfma_f32_16x16x32_bf16(kf[ks][g], qfA[ks], sA[g], 0, 0, 0);
    }
    // --- masks + softmax + P writes ---
    if (kt == qtB) {
#pragma unroll
      for (int g = 0; g < 4; ++g) {
        const int kb = g * 16 + u * 4;
#pragma unroll
        for (int i = 0; i < 4; ++i)
          if (kb + i > wq) sB[g][i] = -1e30f;
      }
    }
    softmax_update(sB, haccB, mB, lB);
    write_p(&Ps[w][1][0], sB, lrow, u);
    if (doA) {
      if (kt == qtA) {
#pragma unroll
        for (int g = 0; g < 4; ++g) {
          const int kb = g * 16 + u * 4;
#pragma unroll
          for (int i = 0; i < 4; ++i)
            if (kb + i > wq) sA[g][i] = -1e30f;
        }
      }
      softmax_update(sA, haccA, mA, lA);
      write_p(&Ps[w][0][0], sA, lrow, u);
    }
    // --- V fragments (shared) + P fragments ---
    bf16x8 vf[2][4], pfB[2], pfA[2];
#pragma unroll
    for (int ks = 0; ks < 2; ++ks) {
      const int c = ks * 64 + u * 16;
#pragma unroll
      for (int g = 0; g < 4; ++g) {
        const int r = g * 16 + lrow;
        vf[ks][g] = *(const bf16x8*)(bufV + ((r * 128 + (c ^ ((r & 7) << 4))) >> 1));
      }
      pfB[ks] = *(const bf16x8*)(&Ps[w][1][0] + ((lrow * 128 + (c ^ ((lrow & 7) << 4))) >> 1));
      if (doA)
        pfA[ks] = *(const bf16x8*)(&Ps[w][0][0] + ((lrow * 128 + (c ^ ((lrow & 7) << 4))) >> 1));
    }
    // --- PV both streams ---
#pragma unroll
    for (int ks = 0; ks < 2; ++ks)
#pragma unroll
      for (int g = 0; g < 4; ++g)
        haccB[g] = __builtin_amdgcn_mfma_f32_16x16x32_bf16(vf[ks][g], pfB[ks], haccB[g], 0, 0, 0);
    if (doA) {
#pragma unroll
      for (int ks = 0; ks < 2; ++ks)
#pragma unroll
        for (int g = 0; g < 4; ++g)
          haccA[g] = __builtin_amdgcn_mfma_f32_16x16x32_bf16(vf[ks][g], pfA[ks], haccA[g], 0, 0, 0);
    }
    __syncthreads(); // prefetch landed + everyone done with cur
  }

  const int b = bh >> 4, h = bh & 15;
  {
    const float inv = 1.0f / lA;
    u16* dst = Hh + ((size_t)b * SEQ + (q0A + lrow)) * DM + h * DH + u * 4;
#pragma unroll
    for (int g = 0; g < 4; ++g) {
      u32x2 pk = { cvtpk(haccA[g][0] * inv, haccA[g][1] * inv),
                   cvtpk(haccA[g][2] * inv, haccA[g][3] * inv) };
      *(u32x2*)(dst + g * 16) = pk;
    }
  }
  {
    const float inv = 1.0f / lB;
    u16* dst = Hh + ((size_t)b * SEQ + (q0B + lrow)) * DM + h * DH + u * 4;
#pragma unroll
    for (int g = 0; g < 4; ++g) {
      u32x2 pk = { cvtpk(haccB[g][0] * inv, haccB[g][1] * inv),
                   cvtpk(haccB[g][2] * inv, haccB[g][3] * inv) };
      *(u32x2*)(dst + g * 16) = pk;
    }
  }
}

extern "C" void kernel_launch(void* const* d_in, const int* in_sizes, int n_in,
                              void* d_out, int out_size, void* d_ws, size_t ws_size,
                              hipStream_t stream) {
  const float* x  = (const float*)d_in[0];
  const float* Wq = (const float*)d_in[1];
  const float* bq = (const float*)d_in[2];
  const float* Wk = (const float*)d_in[3];
  const float* bk = (const float*)d_in[4];
  const float* Wv = (const float*)d_in[5];
  const float* bv = (const float*)d_in[6];
  const float* Wo = (const float*)d_in[7];
  const float* bo = (const float*)d_in[8];
  float* out = (float*)d_out;

  // workspace layout (bytes): total 48 MiB
  char* ws = (char*)d_ws;
  u16* Xb  = (u16*)(ws);                    // 8 MiB  [4096,1024] bf16
  u16* Wt  = (u16*)(ws + (8u << 20));       // 8 MiB  4x [1024,1024] bf16 (transposed)
  u16* Qb  = (u16*)(ws + (16u << 20));      // 8 MiB  [B,H,S,DH]
  u16* Kb  = (u16*)(ws + (24u << 20));      // 8 MiB  [B,H,S,DH]
  u16* Vt  = (u16*)(ws + (32u << 20));      // 8 MiB  [B,H,DH,S]
  u16* Hh  = (u16*)(ws + (40u << 20));      // 8 MiB  [B,S,DM]
  (void)in_sizes; (void)n_in; (void)out_size; (void)ws_size;

  // 1) convert x
  cvt_kernel<<<4096, 256, 0, stream>>>(x, Xb, 4096 * 1024 / 4);
  // 2) transpose+convert weights (one fused launch)
  dim3 tg(32, 32, 4);
  wtrans_kernel<<<tg, 256, 0, stream>>>(Wq, Wk, Wv, Wo, Wt);
  // 3) fused QKV projection: 128x64 tiles -> 1536 blocks (~6/CU)
  dim3 gq(16, 32, 3);
  gemm_kernel<128, 64><<<gq, 256, 0, stream>>>(Xb, Wt, bq, bk, bv, Qb, Kb, Vt, 0);
  // 4) causal flash attention -> Hh [B,S,DM] bf16
  dim3 ga(16, 32);
  attn_kernel<<<ga, 256, 0, stream>>>(Qb, Kb, Vt, Hh);
  // 5) output projection: 64x64 tiles -> 1024 blocks (4/CU)
  dim3 go(16, 64, 1);
  gemm_kernel<64, 64><<<go, 256, 0, stream>>>(Hh, Wt + (3u << 20), bo, bo, bo, out, out, out, 3);
}

// Round 6
// 207.593 us; speedup vs baseline: 1.0310x; 1.0310x over previous
//
#include <hip/hip_runtime.h>

typedef unsigned short u16;
typedef unsigned int u32;
typedef __attribute__((ext_vector_type(8))) __bf16 bf16x8;
typedef __attribute__((ext_vector_type(4))) float f32x4;
typedef __attribute__((ext_vector_type(4))) unsigned short u16x4;
typedef __attribute__((ext_vector_type(2))) unsigned int u32x2;

#define SEQ 2048
#define DM 1024
#define NH 16
#define DH 64
// M = BATCH*SEQ = 4096, N = 1024, K = 1024 for all GEMMs

__device__ __forceinline__ float fexp2(float x) {
  return __builtin_amdgcn_exp2f(x); // raw v_exp_f32 (2^x)
}

__device__ __forceinline__ unsigned short f2bf(float f) {
  unsigned u = __builtin_bit_cast(unsigned, f);
  u += 0x7fffu + ((u >> 16) & 1u);
  return (unsigned short)(u >> 16);
}

__device__ __forceinline__ u32 cvtpk(float lo, float hi) { // {bf16(lo), bf16(hi)}
  u32 r;
  asm("v_cvt_pk_bf16_f32 %0, %1, %2" : "=v"(r) : "v"(lo), "v"(hi));
  return r;
}

__device__ __forceinline__ void gload_lds16(const u16* g, u16* l) {
  __builtin_amdgcn_global_load_lds(
      (const __attribute__((address_space(1))) u16*)g,
      (__attribute__((address_space(3))) u16*)l, 16, 0, 0);
}

// ---------- convert x fp32 -> bf16 ----------
__global__ __launch_bounds__(256) void cvt_kernel(const float* __restrict__ in,
                                                  u16* __restrict__ out, int n4) {
  int id = blockIdx.x * 256 + threadIdx.x;
  if (id >= n4) return;
  float4 v = ((const float4*)in)[id];
  u16x4 o = { f2bf(v.x), f2bf(v.y), f2bf(v.z), f2bf(v.w) };
  ((u16x4*)out)[id] = o;
}

// ---------- transpose + convert weights (all 4 in one launch, z selects) ----
__global__ __launch_bounds__(256) void wtrans_kernel(const float* __restrict__ W0,
                                                     const float* __restrict__ W1,
                                                     const float* __restrict__ W2,
                                                     const float* __restrict__ W3,
                                                     u16* __restrict__ WtBase) {
  const float* W = (blockIdx.z == 0) ? W0 : (blockIdx.z == 1) ? W1
                 : (blockIdx.z == 2) ? W2 : W3;
  u16* Wt = WtBase + ((size_t)blockIdx.z << 20);
  __shared__ float tile[32][33];
  int tx = threadIdx.x & 31, ty = threadIdx.x >> 5; // 32 x 8
  int k0 = blockIdx.y * 32, n0 = blockIdx.x * 32;
#pragma unroll
  for (int j = 0; j < 32; j += 8)
    tile[ty + j][tx] = W[(size_t)(k0 + ty + j) * DM + n0 + tx];
  __syncthreads();
#pragma unroll
  for (int j = 0; j < 32; j += 8)
    Wt[(size_t)(n0 + ty + j) * DM + k0 + tx] = f2bf(tile[tx][ty + j]);
}

// ---------- GEMM v3: BK=64, XOR-swizzled LDS (conflict-free ds_read_b128) ----
// C = A(bf16 [4096,1024]) @ Wt^T + bias
// modes: 0=Q  -> [B,H,S,DH] bf16, scaled by 0.125*log2(e) (softmax in exp2)
//        1=K  -> [B,H,S,DH] bf16
//        2=V  -> [B,H,DH,S] bf16 (transposed for PV A-fragments)
//        3=O  -> [4096,1024] fp32 (final output)
template <int BM, int BN>
__global__ __launch_bounds__(256) void gemm_kernel(
    const u16* __restrict__ A, const u16* __restrict__ WtBase,
    const float* __restrict__ b0, const float* __restrict__ b1,
    const float* __restrict__ b2,
    void* __restrict__ O0, void* __restrict__ O1, void* __restrict__ O2,
    int modeBase) {
  constexpr int MR = BM / 32, NR = BN / 32; // fragments per wave (2x2 wave grid)
  const int Kd = 1024, Nd = 1024;
  const int mode = modeBase + blockIdx.z;
  const u16* Bt = WtBase + ((size_t)blockIdx.z << 20);
  const float* bias = (blockIdx.z == 0) ? b0 : (blockIdx.z == 1) ? b1 : b2;
  void* Out = (blockIdx.z == 0) ? O0 : (blockIdx.z == 1) ? O1 : O2;

  // rows of 64 u16 = 128B, XOR-swizzled: 16B-chunk c ^= (row&7)
  __shared__ u16 As[2][BM * 64];
  __shared__ u16 Bs[2][BN * 64];
  const int tid = threadIdx.x;
  const int lane = tid & 63, w = tid >> 6;
  const int lrow = lane & 15, u = lane >> 4;
  const int wr = w >> 1, wc = w & 1;
  const int brow = blockIdx.y * BM, bcol = blockIdx.x * BN;

  f32x4 acc[MR][NR] = {};

  // staged via pre-swizzled per-lane global source; LDS dest linear (tid*16)
  auto stage = [&](int kt, int buf) {
#pragma unroll
    for (int i = 0; i < BM / 32; ++i) {
      const int p = i * 4096 + tid * 16;          // linear phys byte
      const int row = p >> 7;
      const int chunk = ((p >> 4) & 7) ^ (row & 7);
      gload_lds16(A + (size_t)(brow + row) * Kd + kt + chunk * 8, As[buf] + (p >> 1));
    }
#pragma unroll
    for (int i = 0; i < BN / 32; ++i) {
      const int p = i * 4096 + tid * 16;
      const int row = p >> 7;
      const int chunk = ((p >> 4) & 7) ^ (row & 7);
      gload_lds16(Bt + (size_t)(bcol + row) * Kd + kt + chunk * 8, Bs[buf] + (p >> 1));
    }
  };

  stage(0, 0);
  __syncthreads();

  for (int it = 0; it < 16; ++it) {
    const int cur = it & 1;
    if (it + 1 < 16) stage((it + 1) * 64, cur ^ 1); // prefetch overlaps compute
#pragma unroll
    for (int ks = 0; ks < 2; ++ks) {
      const int c = ks * 64 + u * 16; // byte col within 128B row
      bf16x8 af[MR], bfr[NR];
#pragma unroll
      for (int m = 0; m < MR; ++m) {
        const int r = wr * (BM / 2) + m * 16 + lrow;
        af[m] = *(const bf16x8*)(As[cur] + ((r * 128 + (c ^ ((r & 7) << 4))) >> 1));
      }
#pragma unroll
      for (int n = 0; n < NR; ++n) {
        const int r = wc * (BN / 2) + n * 16 + lrow;
        bfr[n] = *(const bf16x8*)(Bs[cur] + ((r * 128 + (c ^ ((r & 7) << 4))) >> 1));
      }
#pragma unroll
      for (int m = 0; m < MR; ++m)
#pragma unroll
        for (int n = 0; n < NR; ++n)
          acc[m][n] = __builtin_amdgcn_mfma_f32_16x16x32_bf16(af[m], bfr[n], acc[m][n], 0, 0, 0);
    }
    __syncthreads();
  }

  const int r0 = brow + wr * (BM / 2) + u * 4; // + m*16 + i
  const int c0 = bcol + wc * (BN / 2) + lrow;  // + n*16
#pragma unroll
  for (int m = 0; m < MR; ++m) {
#pragma unroll
    for (int n = 0; n < NR; ++n) {
      const int col = c0 + n * 16;
      const float bv = bias[col];
      if (mode == 3) {
        float* O = (float*)Out;
#pragma unroll
        for (int i = 0; i < 4; ++i) {
          int row = r0 + m * 16 + i;
          O[(size_t)row * Nd + col] = acc[m][n][i] + bv;
        }
      } else if (mode == 2) {
        // V transposed: Vt[((b*16+h)*64+dh)*2048 + s], 4 consecutive s per thread
        const int rowb = r0 + m * 16;
        const int b = rowb >> 11, s = rowb & 2047;
        const int h = col >> 6, dh = col & 63;
        u16x4 pk;
#pragma unroll
        for (int i = 0; i < 4; ++i) pk[i] = f2bf(acc[m][n][i] + bv);
        u16* O = (u16*)Out;
        *(u16x4*)(O + ((size_t)((b * NH + h) * DH + dh) * SEQ + s)) = pk;
      } else {
        const float sc = (mode == 0) ? 0.1803368801111204f : 1.0f; // 0.125*log2e
        u16* O = (u16*)Out;
#pragma unroll
        for (int i = 0; i < 4; ++i) {
          int row = r0 + m * 16 + i;
          int b = row >> 11, s = row & 2047;
          int h = col >> 6, dh = col & 63;
          O[((size_t)(b * NH + h) * SEQ + s) * DH + dh] = f2bf((acc[m][n][i] + bv) * sc);
        }
      }
    }
  }
}

// ---------- causal flash attention, v4 (fused A/B streams) ----------
// grid: (16 qpairs, 32 bh). Block = 256 threads = 4 waves.
// Swapped layout: mfma(K,Q) -> lane owns ONE q-row (q=lane&15), k in-lane.
// K/V fragments loaded ONCE per iter, shared by both streams (halves DS reads).
// Softmax: in-lane tree + 2 shuffles + defer-max; P packed via v_cvt_pk_bf16_f32.
__device__ __forceinline__ void softmax_update(f32x4 (&s)[4], f32x4 (&hacc)[4],
                                               float& m_i, float& l_i) {
  float pg0 = fmaxf(fmaxf(s[0][0], s[0][1]), fmaxf(s[0][2], s[0][3]));
  float pg1 = fmaxf(fmaxf(s[1][0], s[1][1]), fmaxf(s[1][2], s[1][3]));
  float pg2 = fmaxf(fmaxf(s[2][0], s[2][1]), fmaxf(s[2][2], s[2][3]));
  float pg3 = fmaxf(fmaxf(s[3][0], s[3][1]), fmaxf(s[3][2], s[3][3]));
  float pmax = fmaxf(fmaxf(pg0, pg1), fmaxf(pg2, pg3));
  pmax = fmaxf(pmax, __shfl_xor(pmax, 16));
  pmax = fmaxf(pmax, __shfl_xor(pmax, 32));
  if (__any(pmax > m_i + 8.0f)) { // defer-max: P bounded by 2^8, bf16-safe
    const float mnew = fmaxf(m_i, pmax);
    const float scl = fexp2(m_i - mnew);
    l_i *= scl;
#pragma unroll
    for (int g = 0; g < 4; ++g) hacc[g] *= scl;
    m_i = mnew;
  }
  float rs = 0.f;
#pragma unroll
  for (int g = 0; g < 4; ++g)
#pragma unroll
    for (int i = 0; i < 4; ++i) {
      const float p = fexp2(s[g][i] - m_i);
      s[g][i] = p;
      rs += p;
    }
  rs += __shfl_xor(rs, 16);
  rs += __shfl_xor(rs, 32);
  l_i += rs;
}

__device__ __forceinline__ void write_p(u16* ps, const f32x4 (&s)[4], int lrow, int u) {
#pragma unroll
  for (int g = 0; g < 4; ++g) {
    u32x2 pw = { cvtpk(s[g][0], s[g][1]), cvtpk(s[g][2], s[g][3]) };
    *(u32x2*)(ps + ((lrow * 128 + ((g * 32 + u * 8) ^ ((lrow & 7) << 4))) >> 1)) = pw;
  }
}

__global__ __launch_bounds__(256, 2) void attn_kernel(const u16* __restrict__ Qb,
                                                      const u16* __restrict__ Kb,
                                                      const u16* __restrict__ Vt,
                                                      u16* __restrict__ Hh) {
  const int px = blockIdx.x, bh = blockIdx.y;
  const int qtA = px, qtB = 31 - px;
  const int tid = threadIdx.x, lane = tid & 63, w = tid >> 6;
  const int lrow = lane & 15, u = lane >> 4;

  const u16* Qp = Qb + (size_t)bh * SEQ * DH;
  const u16* Kp = Kb + (size_t)bh * SEQ * DH;
  const u16* Vp = Vt + (size_t)bh * DH * SEQ;

  __shared__ u16 KV[2][2][4096];   // [buf][K=0/V=1][64x64], swizzled
  __shared__ u16 Ps[4][2][1024];   // [wave][stream][16x64], swizzled

  const int q0A = qtA * 64 + w * 16, q0B = qtB * 64 + w * 16;
  bf16x8 qfA[2], qfB[2];
#pragma unroll
  for (int ks = 0; ks < 2; ++ks) {
    qfA[ks] = *(const bf16x8*)(Qp + (size_t)(q0A + lrow) * DH + ks * 32 + u * 8);
    qfB[ks] = *(const bf16x8*)(Qp + (size_t)(q0B + lrow) * DH + ks * 32 + u * 8);
  }

  float mA = -1e30f, lA = 0.f, mB = -1e30f, lB = 0.f;
  f32x4 haccA[4], haccB[4];
#pragma unroll
  for (int g = 0; g < 4; ++g) {
    haccA[g] = (f32x4){0.f, 0.f, 0.f, 0.f};
    haccB[g] = (f32x4){0.f, 0.f, 0.f, 0.f};
  }

  // cooperative tile stage: 256 thr x 16B x 2 issues per 8KB tile
  auto stage = [&](int kt, int buf) {
#pragma unroll
    for (int i = 0; i < 2; ++i) {
      const int p = i * 4096 + tid * 16;          // linear phys byte in tile
      const int row = p >> 7;                     // 128B rows
      const int c16 = ((p >> 4) & 7) ^ (row & 7); // pre-swizzled source col (16B units)
      gload_lds16(Kp + (size_t)(kt * 64 + row) * 64 + c16 * 8, &KV[buf][0][p >> 1]);
      gload_lds16(Vp + (size_t)row * 2048 + (size_t)kt * 64 + c16 * 8, &KV[buf][1][p >> 1]);
    }
  };

  stage(0, 0);
  __syncthreads();

  const int wq = w * 16 + lrow;
  const int nkt = qtB + 1;
  for (int kt = 0; kt < nkt; ++kt) {
    const int cur = kt & 1;
    if (kt + 1 < nkt) stage(kt + 1, cur ^ 1); // prefetch overlaps compute
    const u16* bufK = KV[cur][0];
    const u16* bufV = KV[cur][1];
    const bool doA = (kt <= qtA);

    // --- K fragments, shared by both streams ---
    bf16x8 kf[2][4];
#pragma unroll
    for (int ks = 0; ks < 2; ++ks) {
      const int c = ks * 64 + u * 16;
#pragma unroll
      for (int g = 0; g < 4; ++g) {
        const int r = g * 16 + lrow;
        kf[ks][g] = *(const bf16x8*)(bufK + ((r * 128 + (c ^ ((r & 7) << 4))) >> 1));
      }
    }
    // --- QK^T both streams (16 independent MFMAs) ---
    f32x4 sA[4] = {}, sB[4] = {};
#pragma unroll
    for (int ks = 0; ks < 2; ++ks)
#pragma unroll
      for (int g = 0; g < 4; ++g)
        sB[g] = __builtin_amdgcn_mfma_f32_16x16x32_bf16(kf[ks][g], qfB[ks], sB[g], 0, 0, 0);
    if (doA) {
#pragma unroll
      for (int ks = 0; ks < 2; ++ks)
#pragma unroll
        for (int g = 0; g < 4; ++g)
          sA[g] = __builtin_amdgcn_mfma_f32_16x16x32_bf16(kf[ks][g], qfA[ks], sA[g], 0, 0, 0);
    }
    // --- masks + softmax + P writes ---
    if (kt == qtB) {
#pragma unroll
      for (int g = 0; g < 4; ++g) {
        const int kb = g * 16 + u * 4;
#pragma unroll
        for (int i = 0; i < 4; ++i)
          if (kb + i > wq) sB[g][i] = -1e30f;
      }
    }
    softmax_update(sB, haccB, mB, lB);
    write_p(&Ps[w][1][0], sB, lrow, u);
    if (doA) {
      if (kt == qtA) {
#pragma unroll
        for (int g = 0; g < 4; ++g) {
          const int kb = g * 16 + u * 4;
#pragma unroll
          for (int i = 0; i < 4; ++i)
            if (kb + i > wq) sA[g][i] = -1e30f;
        }
      }
      softmax_update(sA, haccA, mA, lA);
      write_p(&Ps[w][0][0], sA, lrow, u);
    }
    // --- V fragments (shared) + P fragments ---
    bf16x8 vf[2][4], pfB[2], pfA[2];
#pragma unroll
    for (int ks = 0; ks < 2; ++ks) {
      const int c = ks * 64 + u * 16;
#pragma unroll
      for (int g = 0; g < 4; ++g) {
        const int r = g * 16 + lrow;
        vf[ks][g] = *(const bf16x8*)(bufV + ((r * 128 + (c ^ ((r & 7) << 4))) >> 1));
      }
      pfB[ks] = *(const bf16x8*)(&Ps[w][1][0] + ((lrow * 128 + (c ^ ((lrow & 7) << 4))) >> 1));
      if (doA)
        pfA[ks] = *(const bf16x8*)(&Ps[w][0][0] + ((lrow * 128 + (c ^ ((lrow & 7) << 4))) >> 1));
    }
    // --- PV both streams ---
#pragma unroll
    for (int ks = 0; ks < 2; ++ks)
#pragma unroll
      for (int g = 0; g < 4; ++g)
        haccB[g] = __builtin_amdgcn_mfma_f32_16x16x32_bf16(vf[ks][g], pfB[ks], haccB[g], 0, 0, 0);
    if (doA) {
#pragma unroll
      for (int ks = 0; ks < 2; ++ks)
#pragma unroll
        for (int g = 0; g < 4; ++g)
          haccA[g] = __builtin_amdgcn_mfma_f32_16x16x32_bf16(vf[ks][g], pfA[ks], haccA[g], 0, 0, 0);
    }
    __syncthreads(); // prefetch landed + everyone done with cur
  }

  const int b = bh >> 4, h = bh & 15;
  {
    const float inv = 1.0f / lA;
    u16* dst = Hh + ((size_t)b * SEQ + (q0A + lrow)) * DM + h * DH + u * 4;
#pragma unroll
    for (int g = 0; g < 4; ++g) {
      u32x2 pk = { cvtpk(haccA[g][0] * inv, haccA[g][1] * inv),
                   cvtpk(haccA[g][2] * inv, haccA[g][3] * inv) };
      *(u32x2*)(dst + g * 16) = pk;
    }
  }
  {
    const float inv = 1.0f / lB;
    u16* dst = Hh + ((size_t)b * SEQ + (q0B + lrow)) * DM + h * DH + u * 4;
#pragma unroll
    for (int g = 0; g < 4; ++g) {
      u32x2 pk = { cvtpk(haccB[g][0] * inv, haccB[g][1] * inv),
                   cvtpk(haccB[g][2] * inv, haccB[g][3] * inv) };
      *(u32x2*)(dst + g * 16) = pk;
    }
  }
}

extern "C" void kernel_launch(void* const* d_in, const int* in_sizes, int n_in,
                              void* d_out, int out_size, void* d_ws, size_t ws_size,
                              hipStream_t stream) {
  const float* x  = (const float*)d_in[0];
  const float* Wq = (const float*)d_in[1];
  const float* bq = (const float*)d_in[2];
  const float* Wk = (const float*)d_in[3];
  const float* bk = (const float*)d_in[4];
  const float* Wv = (const float*)d_in[5];
  const float* bv = (const float*)d_in[6];
  const float* Wo = (const float*)d_in[7];
  const float* bo = (const float*)d_in[8];
  float* out = (float*)d_out;

  // workspace layout (bytes): total 48 MiB
  char* ws = (char*)d_ws;
  u16* Xb  = (u16*)(ws);                    // 8 MiB  [4096,1024] bf16
  u16* Wt  = (u16*)(ws + (8u << 20));       // 8 MiB  4x [1024,1024] bf16 (transposed)
  u16* Qb  = (u16*)(ws + (16u << 20));      // 8 MiB  [B,H,S,DH]
  u16* Kb  = (u16*)(ws + (24u << 20));      // 8 MiB  [B,H,S,DH]
  u16* Vt  = (u16*)(ws + (32u << 20));      // 8 MiB  [B,H,DH,S]
  u16* Hh  = (u16*)(ws + (40u << 20));      // 8 MiB  [B,S,DM]
  (void)in_sizes; (void)n_in; (void)out_size; (void)ws_size;

  // 1) convert x
  cvt_kernel<<<4096, 256, 0, stream>>>(x, Xb, 4096 * 1024 / 4);
  // 2) transpose+convert weights (one fused launch)
  dim3 tg(32, 32, 4);
  wtrans_kernel<<<tg, 256, 0, stream>>>(Wq, Wk, Wv, Wo, Wt);
  // 3) fused QKV projection: 128x128, BK=64, swizzled -> 768 blocks (2/CU by LDS)
  dim3 gq(8, 32, 3);
  gemm_kernel<128, 128><<<gq, 256, 0, stream>>>(Xb, Wt, bq, bk, bv, Qb, Kb, Vt, 0);
  // 4) causal flash attention -> Hh [B,S,DM] bf16
  dim3 ga(16, 32);
  attn_kernel<<<ga, 256, 0, stream>>>(Qb, Kb, Vt, Hh);
  // 5) output projection: 128x64, BK=64, swizzled -> 512 blocks (2/CU)
  dim3 go(16, 32, 1);
  gemm_kernel<128, 64><<<go, 256, 0, stream>>>(Hh, Wt + (3u << 20), bo, bo, bo, out, out, out, 3);
}

// Round 7
// 194.457 us; speedup vs baseline: 1.1006x; 1.0676x over previous
//
#include <hip/hip_runtime.h>

typedef unsigned short u16;
typedef unsigned int u32;
typedef __attribute__((ext_vector_type(8))) __bf16 bf16x8;
typedef __attribute__((ext_vector_type(4))) float f32x4;
typedef __attribute__((ext_vector_type(4))) unsigned short u16x4;
typedef __attribute__((ext_vector_type(2))) unsigned int u32x2;

#define SEQ 2048
#define DM 1024
#define NH 16
#define DH 64
// M = BATCH*SEQ = 4096, N = 1024, K = 1024 for all GEMMs

__device__ __forceinline__ float fexp2(float x) {
  return __builtin_amdgcn_exp2f(x); // raw v_exp_f32 (2^x)
}

__device__ __forceinline__ unsigned short f2bf(float f) {
  unsigned u = __builtin_bit_cast(unsigned, f);
  u += 0x7fffu + ((u >> 16) & 1u);
  return (unsigned short)(u >> 16);
}

__device__ __forceinline__ u32 cvtpk(float lo, float hi) { // {bf16(lo), bf16(hi)}
  u32 r;
  asm("v_cvt_pk_bf16_f32 %0, %1, %2" : "=v"(r) : "v"(lo), "v"(hi));
  return r;
}

__device__ __forceinline__ void gload_lds16(const u16* g, u16* l) {
  __builtin_amdgcn_global_load_lds(
      (const __attribute__((address_space(1))) u16*)g,
      (__attribute__((address_space(3))) u16*)l, 16, 0, 0);
}

// ---------- prep: weights transpose+cvt (z<4) and x cvt (z==4) ----------
__global__ __launch_bounds__(256) void prep_kernel(const float* __restrict__ x,
                                                   const float* __restrict__ W0,
                                                   const float* __restrict__ W1,
                                                   const float* __restrict__ W2,
                                                   const float* __restrict__ W3,
                                                   u16* __restrict__ WtBase,
                                                   u16* __restrict__ Xb) {
  if (blockIdx.z == 4) { // cvt x: 1024 blocks x 256 thr x 4 float4
    const int id = (blockIdx.y * 32 + blockIdx.x) * 256 + threadIdx.x;
#pragma unroll
    for (int rep = 0; rep < 4; ++rep) {
      const int idx = rep * 262144 + id;
      float4 v = ((const float4*)x)[idx];
      u16x4 o = { f2bf(v.x), f2bf(v.y), f2bf(v.z), f2bf(v.w) };
      ((u16x4*)Xb)[idx] = o;
    }
    return;
  }
  const float* W = (blockIdx.z == 0) ? W0 : (blockIdx.z == 1) ? W1
                 : (blockIdx.z == 2) ? W2 : W3;
  u16* Wt = WtBase + ((size_t)blockIdx.z << 20);
  __shared__ float tile[32][33];
  int tx = threadIdx.x & 31, ty = threadIdx.x >> 5; // 32 x 8
  int k0 = blockIdx.y * 32, n0 = blockIdx.x * 32;
#pragma unroll
  for (int j = 0; j < 32; j += 8)
    tile[ty + j][tx] = W[(size_t)(k0 + ty + j) * DM + n0 + tx];
  __syncthreads();
#pragma unroll
  for (int j = 0; j < 32; j += 8)
    Wt[(size_t)(n0 + ty + j) * DM + k0 + tx] = f2bf(tile[tx][ty + j]);
}

// ---------- GEMM v4: BK=32, 32KB LDS, ~4 blocks/CU, XOR-swizzled rows ------
// LDS rows = 32 u16 = 64B, 4x16B chunks, chunk ^= (row&3)
// C = A(bf16 [4096,1024]) @ Wt^T + bias
// modes: 0=Q  -> [B,H,S,DH] bf16, scaled by 0.125*log2(e) (softmax in exp2)
//        1=K  -> [B,H,S,DH] bf16
//        2=V  -> [B,H,DH,S] bf16 (transposed for PV A-fragments)
//        3=O  -> [4096,1024] fp32 (final output)
template <int BM, int BN>
__global__ __launch_bounds__(256, 4) void gemm_kernel(
    const u16* __restrict__ A, const u16* __restrict__ WtBase,
    const float* __restrict__ b0, const float* __restrict__ b1,
    const float* __restrict__ b2,
    void* __restrict__ O0, void* __restrict__ O1, void* __restrict__ O2,
    int modeBase) {
  constexpr int MR = BM / 32, NR = BN / 32; // fragments per wave (2x2 wave grid)
  const int Kd = 1024, Nd = 1024;
  const int mode = modeBase + blockIdx.z;
  const u16* Bt = WtBase + ((size_t)blockIdx.z << 20);
  const float* bias = (blockIdx.z == 0) ? b0 : (blockIdx.z == 1) ? b1 : b2;
  void* Out = (blockIdx.z == 0) ? O0 : (blockIdx.z == 1) ? O1 : O2;

  __shared__ u16 As[2][BM * 32];
  __shared__ u16 Bs[2][BN * 32];
  const int tid = threadIdx.x;
  const int lane = tid & 63, w = tid >> 6;
  const int lrow = lane & 15, u = lane >> 4;
  const int wr = w >> 1, wc = w & 1;
  const int brow = blockIdx.y * BM, bcol = blockIdx.x * BN;

  f32x4 acc[MR][NR] = {};

  // staged via pre-swizzled per-lane global source; LDS dest linear (tid*16)
  auto stage = [&](int kt, int buf) {
#pragma unroll
    for (int i = 0; i < BM / 64; ++i) {
      const int p = i * 4096 + tid * 16;        // linear phys byte
      const int row = p >> 6;                   // 64B rows
      const int chunk = ((p >> 4) & 3) ^ (row & 3);
      gload_lds16(A + (size_t)(brow + row) * Kd + kt + chunk * 8, As[buf] + (p >> 1));
    }
#pragma unroll
    for (int i = 0; i < BN / 64; ++i) {
      const int p = i * 4096 + tid * 16;
      const int row = p >> 6;
      const int chunk = ((p >> 4) & 3) ^ (row & 3);
      gload_lds16(Bt + (size_t)(bcol + row) * Kd + kt + chunk * 8, Bs[buf] + (p >> 1));
    }
  };

  stage(0, 0);
  __syncthreads();

  for (int it = 0; it < 32; ++it) {
    const int cur = it & 1;
    if (it + 1 < 32) stage((it + 1) * 32, cur ^ 1); // prefetch overlaps compute
    bf16x8 af[MR], bfr[NR];
#pragma unroll
    for (int m = 0; m < MR; ++m) {
      const int r = wr * (BM / 2) + m * 16 + lrow;
      af[m] = *(const bf16x8*)(As[cur] + ((r * 64 + ((u * 16) ^ ((r & 3) << 4))) >> 1));
    }
#pragma unroll
    for (int n = 0; n < NR; ++n) {
      const int r = wc * (BN / 2) + n * 16 + lrow;
      bfr[n] = *(const bf16x8*)(Bs[cur] + ((r * 64 + ((u * 16) ^ ((r & 3) << 4))) >> 1));
    }
#pragma unroll
    for (int m = 0; m < MR; ++m)
#pragma unroll
      for (int n = 0; n < NR; ++n)
        acc[m][n] = __builtin_amdgcn_mfma_f32_16x16x32_bf16(af[m], bfr[n], acc[m][n], 0, 0, 0);
    __syncthreads();
  }

  const int r0 = brow + wr * (BM / 2) + u * 4; // + m*16 + i
  const int c0 = bcol + wc * (BN / 2) + lrow;  // + n*16
#pragma unroll
  for (int m = 0; m < MR; ++m) {
#pragma unroll
    for (int n = 0; n < NR; ++n) {
      const int col = c0 + n * 16;
      const float bv = bias[col];
      if (mode == 3) {
        float* O = (float*)Out;
#pragma unroll
        for (int i = 0; i < 4; ++i) {
          int row = r0 + m * 16 + i;
          O[(size_t)row * Nd + col] = acc[m][n][i] + bv;
        }
      } else if (mode == 2) {
        // V transposed: Vt[((b*16+h)*64+dh)*2048 + s], 4 consecutive s per thread
        const int rowb = r0 + m * 16;
        const int b = rowb >> 11, s = rowb & 2047;
        const int h = col >> 6, dh = col & 63;
        u16x4 pk;
#pragma unroll
        for (int i = 0; i < 4; ++i) pk[i] = f2bf(acc[m][n][i] + bv);
        u16* O = (u16*)Out;
        *(u16x4*)(O + ((size_t)((b * NH + h) * DH + dh) * SEQ + s)) = pk;
      } else {
        const float sc = (mode == 0) ? 0.1803368801111204f : 1.0f; // 0.125*log2e
        u16* O = (u16*)Out;
#pragma unroll
        for (int i = 0; i < 4; ++i) {
          int row = r0 + m * 16 + i;
          int b = row >> 11, s = row & 2047;
          int h = col >> 6, dh = col & 63;
          O[((size_t)(b * NH + h) * SEQ + s) * DH + dh] = f2bf((acc[m][n][i] + bv) * sc);
        }
      }
    }
  }
}

// ---------- causal flash attention, v4 (fused A/B streams) ----------
// grid: (16 qpairs, 32 bh). Block = 256 threads = 4 waves.
// Swapped layout: mfma(K,Q) -> lane owns ONE q-row (q=lane&15), k in-lane.
// K/V fragments loaded ONCE per iter, shared by both streams (halves DS reads).
// Softmax: in-lane tree + 2 shuffles + defer-max; P packed via v_cvt_pk_bf16_f32.
__device__ __forceinline__ void softmax_update(f32x4 (&s)[4], f32x4 (&hacc)[4],
                                               float& m_i, float& l_i) {
  float pg0 = fmaxf(fmaxf(s[0][0], s[0][1]), fmaxf(s[0][2], s[0][3]));
  float pg1 = fmaxf(fmaxf(s[1][0], s[1][1]), fmaxf(s[1][2], s[1][3]));
  float pg2 = fmaxf(fmaxf(s[2][0], s[2][1]), fmaxf(s[2][2], s[2][3]));
  float pg3 = fmaxf(fmaxf(s[3][0], s[3][1]), fmaxf(s[3][2], s[3][3]));
  float pmax = fmaxf(fmaxf(pg0, pg1), fmaxf(pg2, pg3));
  pmax = fmaxf(pmax, __shfl_xor(pmax, 16));
  pmax = fmaxf(pmax, __shfl_xor(pmax, 32));
  if (__any(pmax > m_i + 8.0f)) { // defer-max: P bounded by 2^8, bf16-safe
    const float mnew = fmaxf(m_i, pmax);
    const float scl = fexp2(m_i - mnew);
    l_i *= scl;
#pragma unroll
    for (int g = 0; g < 4; ++g) hacc[g] *= scl;
    m_i = mnew;
  }
  float rs = 0.f;
#pragma unroll
  for (int g = 0; g < 4; ++g)
#pragma unroll
    for (int i = 0; i < 4; ++i) {
      const float p = fexp2(s[g][i] - m_i);
      s[g][i] = p;
      rs += p;
    }
  rs += __shfl_xor(rs, 16);
  rs += __shfl_xor(rs, 32);
  l_i += rs;
}

__device__ __forceinline__ void write_p(u16* ps, const f32x4 (&s)[4], int lrow, int u) {
#pragma unroll
  for (int g = 0; g < 4; ++g) {
    u32x2 pw = { cvtpk(s[g][0], s[g][1]), cvtpk(s[g][2], s[g][3]) };
    *(u32x2*)(ps + ((lrow * 128 + ((g * 32 + u * 8) ^ ((lrow & 7) << 4))) >> 1)) = pw;
  }
}

__global__ __launch_bounds__(256, 2) void attn_kernel(const u16* __restrict__ Qb,
                                                      const u16* __restrict__ Kb,
                                                      const u16* __restrict__ Vt,
                                                      u16* __restrict__ Hh) {
  const int px = blockIdx.x, bh = blockIdx.y;
  const int qtA = px, qtB = 31 - px;
  const int tid = threadIdx.x, lane = tid & 63, w = tid >> 6;
  const int lrow = lane & 15, u = lane >> 4;

  const u16* Qp = Qb + (size_t)bh * SEQ * DH;
  const u16* Kp = Kb + (size_t)bh * SEQ * DH;
  const u16* Vp = Vt + (size_t)bh * DH * SEQ;

  __shared__ u16 KV[2][2][4096];   // [buf][K=0/V=1][64x64], swizzled
  __shared__ u16 Ps[4][2][1024];   // [wave][stream][16x64], swizzled

  const int q0A = qtA * 64 + w * 16, q0B = qtB * 64 + w * 16;
  bf16x8 qfA[2], qfB[2];
#pragma unroll
  for (int ks = 0; ks < 2; ++ks) {
    qfA[ks] = *(const bf16x8*)(Qp + (size_t)(q0A + lrow) * DH + ks * 32 + u * 8);
    qfB[ks] = *(const bf16x8*)(Qp + (size_t)(q0B + lrow) * DH + ks * 32 + u * 8);
  }

  float mA = -1e30f, lA = 0.f, mB = -1e30f, lB = 0.f;
  f32x4 haccA[4], haccB[4];
#pragma unroll
  for (int g = 0; g < 4; ++g) {
    haccA[g] = (f32x4){0.f, 0.f, 0.f, 0.f};
    haccB[g] = (f32x4){0.f, 0.f, 0.f, 0.f};
  }

  // cooperative tile stage: 256 thr x 16B x 2 issues per 8KB tile
  auto stage = [&](int kt, int buf) {
#pragma unroll
    for (int i = 0; i < 2; ++i) {
      const int p = i * 4096 + tid * 16;          // linear phys byte in tile
      const int row = p >> 7;                     // 128B rows
      const int c16 = ((p >> 4) & 7) ^ (row & 7); // pre-swizzled source col (16B units)
      gload_lds16(Kp + (size_t)(kt * 64 + row) * 64 + c16 * 8, &KV[buf][0][p >> 1]);
      gload_lds16(Vp + (size_t)row * 2048 + (size_t)kt * 64 + c16 * 8, &KV[buf][1][p >> 1]);
    }
  };

  stage(0, 0);
  __syncthreads();

  const int wq = w * 16 + lrow;
  const int nkt = qtB + 1;
  for (int kt = 0; kt < nkt; ++kt) {
    const int cur = kt & 1;
    if (kt + 1 < nkt) stage(kt + 1, cur ^ 1); // prefetch overlaps compute
    const u16* bufK = KV[cur][0];
    const u16* bufV = KV[cur][1];
    const bool doA = (kt <= qtA);

    // --- K fragments, shared by both streams ---
    bf16x8 kf[2][4];
#pragma unroll
    for (int ks = 0; ks < 2; ++ks) {
      const int c = ks * 64 + u * 16;
#pragma unroll
      for (int g = 0; g < 4; ++g) {
        const int r = g * 16 + lrow;
        kf[ks][g] = *(const bf16x8*)(bufK + ((r * 128 + (c ^ ((r & 7) << 4))) >> 1));
      }
    }
    // --- QK^T both streams (16 independent MFMAs) ---
    f32x4 sA[4] = {}, sB[4] = {};
#pragma unroll
    for (int ks = 0; ks < 2; ++ks)
#pragma unroll
      for (int g = 0; g < 4; ++g)
        sB[g] = __builtin_amdgcn_mfma_f32_16x16x32_bf16(kf[ks][g], qfB[ks], sB[g], 0, 0, 0);
    if (doA) {
#pragma unroll
      for (int ks = 0; ks < 2; ++ks)
#pragma unroll
        for (int g = 0; g < 4; ++g)
          sA[g] = __builtin_amdgcn_mfma_f32_16x16x32_bf16(kf[ks][g], qfA[ks], sA[g], 0, 0, 0);
    }
    // --- masks + softmax + P writes ---
    if (kt == qtB) {
#pragma unroll
      for (int g = 0; g < 4; ++g) {
        const int kb = g * 16 + u * 4;
#pragma unroll
        for (int i = 0; i < 4; ++i)
          if (kb + i > wq) sB[g][i] = -1e30f;
      }
    }
    softmax_update(sB, haccB, mB, lB);
    write_p(&Ps[w][1][0], sB, lrow, u);
    if (doA) {
      if (kt == qtA) {
#pragma unroll
        for (int g = 0; g < 4; ++g) {
          const int kb = g * 16 + u * 4;
#pragma unroll
          for (int i = 0; i < 4; ++i)
            if (kb + i > wq) sA[g][i] = -1e30f;
        }
      }
      softmax_update(sA, haccA, mA, lA);
      write_p(&Ps[w][0][0], sA, lrow, u);
    }
    // --- V fragments (shared) + P fragments ---
    bf16x8 vf[2][4], pfB[2], pfA[2];
#pragma unroll
    for (int ks = 0; ks < 2; ++ks) {
      const int c = ks * 64 + u * 16;
#pragma unroll
      for (int g = 0; g < 4; ++g) {
        const int r = g * 16 + lrow;
        vf[ks][g] = *(const bf16x8*)(bufV + ((r * 128 + (c ^ ((r & 7) << 4))) >> 1));
      }
      pfB[ks] = *(const bf16x8*)(&Ps[w][1][0] + ((lrow * 128 + (c ^ ((lrow & 7) << 4))) >> 1));
      if (doA)
        pfA[ks] = *(const bf16x8*)(&Ps[w][0][0] + ((lrow * 128 + (c ^ ((lrow & 7) << 4))) >> 1));
    }
    // --- PV both streams ---
#pragma unroll
    for (int ks = 0; ks < 2; ++ks)
#pragma unroll
      for (int g = 0; g < 4; ++g)
        haccB[g] = __builtin_amdgcn_mfma_f32_16x16x32_bf16(vf[ks][g], pfB[ks], haccB[g], 0, 0, 0);
    if (doA) {
#pragma unroll
      for (int ks = 0; ks < 2; ++ks)
#pragma unroll
        for (int g = 0; g < 4; ++g)
          haccA[g] = __builtin_amdgcn_mfma_f32_16x16x32_bf16(vf[ks][g], pfA[ks], haccA[g], 0, 0, 0);
    }
    __syncthreads(); // prefetch landed + everyone done with cur
  }

  const int b = bh >> 4, h = bh & 15;
  {
    const float inv = 1.0f / lA;
    u16* dst = Hh + ((size_t)b * SEQ + (q0A + lrow)) * DM + h * DH + u * 4;
#pragma unroll
    for (int g = 0; g < 4; ++g) {
      u32x2 pk = { cvtpk(haccA[g][0] * inv, haccA[g][1] * inv),
                   cvtpk(haccA[g][2] * inv, haccA[g][3] * inv) };
      *(u32x2*)(dst + g * 16) = pk;
    }
  }
  {
    const float inv = 1.0f / lB;
    u16* dst = Hh + ((size_t)b * SEQ + (q0B + lrow)) * DM + h * DH + u * 4;
#pragma unroll
    for (int g = 0; g < 4; ++g) {
      u32x2 pk = { cvtpk(haccB[g][0] * inv, haccB[g][1] * inv),
                   cvtpk(haccB[g][2] * inv, haccB[g][3] * inv) };
      *(u32x2*)(dst + g * 16) = pk;
    }
  }
}

extern "C" void kernel_launch(void* const* d_in, const int* in_sizes, int n_in,
                              void* d_out, int out_size, void* d_ws, size_t ws_size,
                              hipStream_t stream) {
  const float* x  = (const float*)d_in[0];
  const float* Wq = (const float*)d_in[1];
  const float* bq = (const float*)d_in[2];
  const float* Wk = (const float*)d_in[3];
  const float* bk = (const float*)d_in[4];
  const float* Wv = (const float*)d_in[5];
  const float* bv = (const float*)d_in[6];
  const float* Wo = (const float*)d_in[7];
  const float* bo = (const float*)d_in[8];
  float* out = (float*)d_out;

  // workspace layout (bytes): total 48 MiB
  char* ws = (char*)d_ws;
  u16* Xb  = (u16*)(ws);                    // 8 MiB  [4096,1024] bf16
  u16* Wt  = (u16*)(ws + (8u << 20));       // 8 MiB  4x [1024,1024] bf16 (transposed)
  u16* Qb  = (u16*)(ws + (16u << 20));      // 8 MiB  [B,H,S,DH]
  u16* Kb  = (u16*)(ws + (24u << 20));      // 8 MiB  [B,H,S,DH]
  u16* Vt  = (u16*)(ws + (32u << 20));      // 8 MiB  [B,H,DH,S]
  u16* Hh  = (u16*)(ws + (40u << 20));      // 8 MiB  [B,S,DM]
  (void)in_sizes; (void)n_in; (void)out_size; (void)ws_size;

  // 1) prep: x cvt + 4 weight transposes in one launch
  dim3 tp(32, 32, 5);
  prep_kernel<<<tp, 256, 0, stream>>>(x, Wq, Wk, Wv, Wo, Wt, Xb);
  // 2) fused QKV projection: 128x128, BK=32, swizzled -> 768 blocks (~4/CU)
  dim3 gq(8, 32, 3);
  gemm_kernel<128, 128><<<gq, 256, 0, stream>>>(Xb, Wt, bq, bk, bv, Qb, Kb, Vt, 0);
  // 3) causal flash attention -> Hh [B,S,DM] bf16
  dim3 ga(16, 32);
  attn_kernel<<<ga, 256, 0, stream>>>(Qb, Kb, Vt, Hh);
  // 4) output projection: 128x64, BK=32, swizzled -> 512 blocks
  dim3 go(16, 32, 1);
  gemm_kernel<128, 64><<<go, 256, 0, stream>>>(Hh, Wt + (3u << 20), bo, bo, bo, out, out, out, 3);
}

// Round 8
// 194.344 us; speedup vs baseline: 1.1012x; 1.0006x over previous
//
#include <hip/hip_runtime.h>

typedef unsigned short u16;
typedef unsigned int u32;
typedef __attribute__((ext_vector_type(8))) __bf16 bf16x8;
typedef __attribute__((ext_vector_type(4))) float f32x4;
typedef __attribute__((ext_vector_type(4))) unsigned short u16x4;
typedef __attribute__((ext_vector_type(2))) unsigned int u32x2;

#define SEQ 2048
#define DM 1024
#define NH 16
#define DH 64
// M = BATCH*SEQ = 4096, N = 1024, K = 1024 for all GEMMs

__device__ __forceinline__ float fexp2(float x) {
  return __builtin_amdgcn_exp2f(x); // raw v_exp_f32 (2^x)
}

__device__ __forceinline__ unsigned short f2bf(float f) {
  unsigned u = __builtin_bit_cast(unsigned, f);
  u += 0x7fffu + ((u >> 16) & 1u);
  return (unsigned short)(u >> 16);
}

__device__ __forceinline__ u32 cvtpk(float lo, float hi) { // {bf16(lo), bf16(hi)}
  u32 r;
  asm("v_cvt_pk_bf16_f32 %0, %1, %2" : "=v"(r) : "v"(lo), "v"(hi));
  return r;
}

__device__ __forceinline__ void gload_lds16(const u16* g, u16* l) {
  __builtin_amdgcn_global_load_lds(
      (const __attribute__((address_space(1))) u16*)g,
      (__attribute__((address_space(3))) u16*)l, 16, 0, 0);
}

// ---------- prep: weights transpose+cvt (z<4) and x cvt (z==4) ----------
__global__ __launch_bounds__(256) void prep_kernel(const float* __restrict__ x,
                                                   const float* __restrict__ W0,
                                                   const float* __restrict__ W1,
                                                   const float* __restrict__ W2,
                                                   const float* __restrict__ W3,
                                                   u16* __restrict__ WtBase,
                                                   u16* __restrict__ Xb) {
  if (blockIdx.z == 4) { // cvt x: 1024 blocks x 256 thr x 4 float4
    const int id = (blockIdx.y * 32 + blockIdx.x) * 256 + threadIdx.x;
#pragma unroll
    for (int rep = 0; rep < 4; ++rep) {
      const int idx = rep * 262144 + id;
      float4 v = ((const float4*)x)[idx];
      u16x4 o = { f2bf(v.x), f2bf(v.y), f2bf(v.z), f2bf(v.w) };
      ((u16x4*)Xb)[idx] = o;
    }
    return;
  }
  const float* W = (blockIdx.z == 0) ? W0 : (blockIdx.z == 1) ? W1
                 : (blockIdx.z == 2) ? W2 : W3;
  u16* Wt = WtBase + ((size_t)blockIdx.z << 20);
  __shared__ float tile[32][33];
  int tx = threadIdx.x & 31, ty = threadIdx.x >> 5; // 32 x 8
  int k0 = blockIdx.y * 32, n0 = blockIdx.x * 32;
#pragma unroll
  for (int j = 0; j < 32; j += 8)
    tile[ty + j][tx] = W[(size_t)(k0 + ty + j) * DM + n0 + tx];
  __syncthreads();
#pragma unroll
  for (int j = 0; j < 32; j += 8)
    Wt[(size_t)(n0 + ty + j) * DM + k0 + tx] = f2bf(tile[tx][ty + j]);
}

// ---------- GEMM v5: BK=32 swizzled + XCD-aware block remap ----------
// XCD xcd (=rawid%8) owns row-tiles iy in [xcd*4, xcd*4+4): A-band 1MB stays
// L2-resident; B weights stream once (L3 catches cross-XCD rereads).
// modes: 0=Q -> [B,H,S,DH] bf16 *0.125*log2e; 1=K; 2=V -> [B,H,DH,S]; 3=O fp32
template <int BM, int BN, int GX>
__global__ __launch_bounds__(256, 4) void gemm_kernel(
    const u16* __restrict__ A, const u16* __restrict__ WtBase,
    const float* __restrict__ b0, const float* __restrict__ b1,
    const float* __restrict__ b2,
    void* __restrict__ O0, void* __restrict__ O1, void* __restrict__ O2,
    int modeBase) {
  constexpr int MR = BM / 32, NR = BN / 32; // fragments per wave (2x2 wave grid)
  const int Kd = 1024, Nd = 1024;
  // XCD-aware bijective remap: rawid%8 = XCD (round-robin dispatch)
  const int rawid = (blockIdx.z * 32 + blockIdx.y) * GX + blockIdx.x;
  const int xcd = rawid & 7, slot = rawid >> 3;
  const int iy = xcd * 4 + (slot & 3);
  const int ix = (slot >> 2) % GX;
  const int iz = slot / (4 * GX);

  const int mode = modeBase + iz;
  const u16* Bt = WtBase + ((size_t)iz << 20);
  const float* bias = (iz == 0) ? b0 : (iz == 1) ? b1 : b2;
  void* Out = (iz == 0) ? O0 : (iz == 1) ? O1 : O2;

  __shared__ u16 As[2][BM * 32];
  __shared__ u16 Bs[2][BN * 32];
  const int tid = threadIdx.x;
  const int lane = tid & 63, w = tid >> 6;
  const int lrow = lane & 15, u = lane >> 4;
  const int wr = w >> 1, wc = w & 1;
  const int brow = iy * BM, bcol = ix * BN;

  f32x4 acc[MR][NR] = {};

  // staged via pre-swizzled per-lane global source; LDS dest linear (tid*16)
  auto stage = [&](int kt, int buf) {
#pragma unroll
    for (int i = 0; i < BM / 64; ++i) {
      const int p = i * 4096 + tid * 16;        // linear phys byte
      const int row = p >> 6;                   // 64B rows
      const int chunk = ((p >> 4) & 3) ^ (row & 3);
      gload_lds16(A + (size_t)(brow + row) * Kd + kt + chunk * 8, As[buf] + (p >> 1));
    }
#pragma unroll
    for (int i = 0; i < BN / 64; ++i) {
      const int p = i * 4096 + tid * 16;
      const int row = p >> 6;
      const int chunk = ((p >> 4) & 3) ^ (row & 3);
      gload_lds16(Bt + (size_t)(bcol + row) * Kd + kt + chunk * 8, Bs[buf] + (p >> 1));
    }
  };

  stage(0, 0);
  __syncthreads();

  for (int it = 0; it < 32; ++it) {
    const int cur = it & 1;
    if (it + 1 < 32) stage((it + 1) * 32, cur ^ 1); // prefetch overlaps compute
    bf16x8 af[MR], bfr[NR];
#pragma unroll
    for (int m = 0; m < MR; ++m) {
      const int r = wr * (BM / 2) + m * 16 + lrow;
      af[m] = *(const bf16x8*)(As[cur] + ((r * 64 + ((u * 16) ^ ((r & 3) << 4))) >> 1));
    }
#pragma unroll
    for (int n = 0; n < NR; ++n) {
      const int r = wc * (BN / 2) + n * 16 + lrow;
      bfr[n] = *(const bf16x8*)(Bs[cur] + ((r * 64 + ((u * 16) ^ ((r & 3) << 4))) >> 1));
    }
#pragma unroll
    for (int m = 0; m < MR; ++m)
#pragma unroll
      for (int n = 0; n < NR; ++n)
        acc[m][n] = __builtin_amdgcn_mfma_f32_16x16x32_bf16(af[m], bfr[n], acc[m][n], 0, 0, 0);
    __syncthreads();
  }

  const int r0 = brow + wr * (BM / 2) + u * 4; // + m*16 + i
  const int c0 = bcol + wc * (BN / 2) + lrow;  // + n*16
#pragma unroll
  for (int m = 0; m < MR; ++m) {
#pragma unroll
    for (int n = 0; n < NR; ++n) {
      const int col = c0 + n * 16;
      const float bv = bias[col];
      if (mode == 3) {
        float* O = (float*)Out;
#pragma unroll
        for (int i = 0; i < 4; ++i) {
          int row = r0 + m * 16 + i;
          O[(size_t)row * Nd + col] = acc[m][n][i] + bv;
        }
      } else if (mode == 2) {
        // V transposed: Vt[((b*16+h)*64+dh)*2048 + s], 4 consecutive s per thread
        const int rowb = r0 + m * 16;
        const int b = rowb >> 11, s = rowb & 2047;
        const int h = col >> 6, dh = col & 63;
        u16x4 pk;
#pragma unroll
        for (int i = 0; i < 4; ++i) pk[i] = f2bf(acc[m][n][i] + bv);
        u16* O = (u16*)Out;
        *(u16x4*)(O + ((size_t)((b * NH + h) * DH + dh) * SEQ + s)) = pk;
      } else {
        const float sc = (mode == 0) ? 0.1803368801111204f : 1.0f; // 0.125*log2e
        u16* O = (u16*)Out;
#pragma unroll
        for (int i = 0; i < 4; ++i) {
          int row = r0 + m * 16 + i;
          int b = row >> 11, s = row & 2047;
          int h = col >> 6, dh = col & 63;
          O[((size_t)(b * NH + h) * SEQ + s) * DH + dh] = f2bf((acc[m][n][i] + bv) * sc);
        }
      }
    }
  }
}

// ---------- causal flash attention, v5 (XCD head-grouping + setprio) -------
// XCD xcd owns 4 heads -> that head's 512KB K/V stays L2-resident; the
// per-iter barrier's vmcnt drain becomes an L2-latency wait, not HBM.
__device__ __forceinline__ void softmax_update(f32x4 (&s)[4], f32x4 (&hacc)[4],
                                               float& m_i, float& l_i) {
  float pg0 = fmaxf(fmaxf(s[0][0], s[0][1]), fmaxf(s[0][2], s[0][3]));
  float pg1 = fmaxf(fmaxf(s[1][0], s[1][1]), fmaxf(s[1][2], s[1][3]));
  float pg2 = fmaxf(fmaxf(s[2][0], s[2][1]), fmaxf(s[2][2], s[2][3]));
  float pg3 = fmaxf(fmaxf(s[3][0], s[3][1]), fmaxf(s[3][2], s[3][3]));
  float pmax = fmaxf(fmaxf(pg0, pg1), fmaxf(pg2, pg3));
  pmax = fmaxf(pmax, __shfl_xor(pmax, 16));
  pmax = fmaxf(pmax, __shfl_xor(pmax, 32));
  if (__any(pmax > m_i + 8.0f)) { // defer-max: P bounded by 2^8, bf16-safe
    const float mnew = fmaxf(m_i, pmax);
    const float scl = fexp2(m_i - mnew);
    l_i *= scl;
#pragma unroll
    for (int g = 0; g < 4; ++g) hacc[g] *= scl;
    m_i = mnew;
  }
  float rs = 0.f;
#pragma unroll
  for (int g = 0; g < 4; ++g)
#pragma unroll
    for (int i = 0; i < 4; ++i) {
      const float p = fexp2(s[g][i] - m_i);
      s[g][i] = p;
      rs += p;
    }
  rs += __shfl_xor(rs, 16);
  rs += __shfl_xor(rs, 32);
  l_i += rs;
}

__device__ __forceinline__ void write_p(u16* ps, const f32x4 (&s)[4], int lrow, int u) {
#pragma unroll
  for (int g = 0; g < 4; ++g) {
    u32x2 pw = { cvtpk(s[g][0], s[g][1]), cvtpk(s[g][2], s[g][3]) };
    *(u32x2*)(ps + ((lrow * 128 + ((g * 32 + u * 8) ^ ((lrow & 7) << 4))) >> 1)) = pw;
  }
}

__global__ __launch_bounds__(256, 2) void attn_kernel(const u16* __restrict__ Qb,
                                                      const u16* __restrict__ Kb,
                                                      const u16* __restrict__ Vt,
                                                      u16* __restrict__ Hh) {
  // XCD-aware remap: 4 heads per XCD, 16 q-pair blocks per head co-located
  const int rawid = blockIdx.y * 16 + blockIdx.x;
  const int xcd = rawid & 7, slot = rawid >> 3;
  const int bh = xcd * 4 + (slot >> 4);
  const int px = slot & 15;
  const int qtA = px, qtB = 31 - px;
  const int tid = threadIdx.x, lane = tid & 63, w = tid >> 6;
  const int lrow = lane & 15, u = lane >> 4;

  const u16* Qp = Qb + (size_t)bh * SEQ * DH;
  const u16* Kp = Kb + (size_t)bh * SEQ * DH;
  const u16* Vp = Vt + (size_t)bh * DH * SEQ;

  __shared__ u16 KV[2][2][4096];   // [buf][K=0/V=1][64x64], swizzled
  __shared__ u16 Ps[4][2][1024];   // [wave][stream][16x64], swizzled

  const int q0A = qtA * 64 + w * 16, q0B = qtB * 64 + w * 16;
  bf16x8 qfA[2], qfB[2];
#pragma unroll
  for (int ks = 0; ks < 2; ++ks) {
    qfA[ks] = *(const bf16x8*)(Qp + (size_t)(q0A + lrow) * DH + ks * 32 + u * 8);
    qfB[ks] = *(const bf16x8*)(Qp + (size_t)(q0B + lrow) * DH + ks * 32 + u * 8);
  }

  float mA = -1e30f, lA = 0.f, mB = -1e30f, lB = 0.f;
  f32x4 haccA[4], haccB[4];
#pragma unroll
  for (int g = 0; g < 4; ++g) {
    haccA[g] = (f32x4){0.f, 0.f, 0.f, 0.f};
    haccB[g] = (f32x4){0.f, 0.f, 0.f, 0.f};
  }

  // cooperative tile stage: 256 thr x 16B x 2 issues per 8KB tile
  auto stage = [&](int kt, int buf) {
#pragma unroll
    for (int i = 0; i < 2; ++i) {
      const int p = i * 4096 + tid * 16;          // linear phys byte in tile
      const int row = p >> 7;                     // 128B rows
      const int c16 = ((p >> 4) & 7) ^ (row & 7); // pre-swizzled source col (16B units)
      gload_lds16(Kp + (size_t)(kt * 64 + row) * 64 + c16 * 8, &KV[buf][0][p >> 1]);
      gload_lds16(Vp + (size_t)row * 2048 + (size_t)kt * 64 + c16 * 8, &KV[buf][1][p >> 1]);
    }
  };

  stage(0, 0);
  __syncthreads();

  const int wq = w * 16 + lrow;
  const int nkt = qtB + 1;
  for (int kt = 0; kt < nkt; ++kt) {
    const int cur = kt & 1;
    if (kt + 1 < nkt) stage(kt + 1, cur ^ 1); // prefetch overlaps compute
    const u16* bufK = KV[cur][0];
    const u16* bufV = KV[cur][1];
    const bool doA = (kt <= qtA);

    // --- K fragments, shared by both streams ---
    bf16x8 kf[2][4];
#pragma unroll
    for (int ks = 0; ks < 2; ++ks) {
      const int c = ks * 64 + u * 16;
#pragma unroll
      for (int g = 0; g < 4; ++g) {
        const int r = g * 16 + lrow;
        kf[ks][g] = *(const bf16x8*)(bufK + ((r * 128 + (c ^ ((r & 7) << 4))) >> 1));
      }
    }
    // --- QK^T both streams (16 independent MFMAs) ---
    f32x4 sA[4] = {}, sB[4] = {};
    __builtin_amdgcn_s_setprio(1);
#pragma unroll
    for (int ks = 0; ks < 2; ++ks)
#pragma unroll
      for (int g = 0; g < 4; ++g)
        sB[g] = __builtin_amdgcn_mfma_f32_16x16x32_bf16(kf[ks][g], qfB[ks], sB[g], 0, 0, 0);
    if (doA) {
#pragma unroll
      for (int ks = 0; ks < 2; ++ks)
#pragma unroll
        for (int g = 0; g < 4; ++g)
          sA[g] = __builtin_amdgcn_mfma_f32_16x16x32_bf16(kf[ks][g], qfA[ks], sA[g], 0, 0, 0);
    }
    __builtin_amdgcn_s_setprio(0);
    // --- masks + softmax + P writes ---
    if (kt == qtB) {
#pragma unroll
      for (int g = 0; g < 4; ++g) {
        const int kb = g * 16 + u * 4;
#pragma unroll
        for (int i = 0; i < 4; ++i)
          if (kb + i > wq) sB[g][i] = -1e30f;
      }
    }
    softmax_update(sB, haccB, mB, lB);
    write_p(&Ps[w][1][0], sB, lrow, u);
    if (doA) {
      if (kt == qtA) {
#pragma unroll
        for (int g = 0; g < 4; ++g) {
          const int kb = g * 16 + u * 4;
#pragma unroll
          for (int i = 0; i < 4; ++i)
            if (kb + i > wq) sA[g][i] = -1e30f;
        }
      }
      softmax_update(sA, haccA, mA, lA);
      write_p(&Ps[w][0][0], sA, lrow, u);
    }
    // --- V fragments (shared) + P fragments ---
    bf16x8 vf[2][4], pfB[2], pfA[2];
#pragma unroll
    for (int ks = 0; ks < 2; ++ks) {
      const int c = ks * 64 + u * 16;
#pragma unroll
      for (int g = 0; g < 4; ++g) {
        const int r = g * 16 + lrow;
        vf[ks][g] = *(const bf16x8*)(bufV + ((r * 128 + (c ^ ((r & 7) << 4))) >> 1));
      }
      pfB[ks] = *(const bf16x8*)(&Ps[w][1][0] + ((lrow * 128 + (c ^ ((lrow & 7) << 4))) >> 1));
      if (doA)
        pfA[ks] = *(const bf16x8*)(&Ps[w][0][0] + ((lrow * 128 + (c ^ ((lrow & 7) << 4))) >> 1));
    }
    // --- PV both streams ---
    __builtin_amdgcn_s_setprio(1);
#pragma unroll
    for (int ks = 0; ks < 2; ++ks)
#pragma unroll
      for (int g = 0; g < 4; ++g)
        haccB[g] = __builtin_amdgcn_mfma_f32_16x16x32_bf16(vf[ks][g], pfB[ks], haccB[g], 0, 0, 0);
    if (doA) {
#pragma unroll
      for (int ks = 0; ks < 2; ++ks)
#pragma unroll
        for (int g = 0; g < 4; ++g)
          haccA[g] = __builtin_amdgcn_mfma_f32_16x16x32_bf16(vf[ks][g], pfA[ks], haccA[g], 0, 0, 0);
    }
    __builtin_amdgcn_s_setprio(0);
    __syncthreads(); // prefetch landed + everyone done with cur
  }

  const int b = bh >> 4, h = bh & 15;
  {
    const float inv = 1.0f / lA;
    u16* dst = Hh + ((size_t)b * SEQ + (q0A + lrow)) * DM + h * DH + u * 4;
#pragma unroll
    for (int g = 0; g < 4; ++g) {
      u32x2 pk = { cvtpk(haccA[g][0] * inv, haccA[g][1] * inv),
                   cvtpk(haccA[g][2] * inv, haccA[g][3] * inv) };
      *(u32x2*)(dst + g * 16) = pk;
    }
  }
  {
    const float inv = 1.0f / lB;
    u16* dst = Hh + ((size_t)b * SEQ + (q0B + lrow)) * DM + h * DH + u * 4;
#pragma unroll
    for (int g = 0; g < 4; ++g) {
      u32x2 pk = { cvtpk(haccB[g][0] * inv, haccB[g][1] * inv),
                   cvtpk(haccB[g][2] * inv, haccB[g][3] * inv) };
      *(u32x2*)(dst + g * 16) = pk;
    }
  }
}

extern "C" void kernel_launch(void* const* d_in, const int* in_sizes, int n_in,
                              void* d_out, int out_size, void* d_ws, size_t ws_size,
                              hipStream_t stream) {
  const float* x  = (const float*)d_in[0];
  const float* Wq = (const float*)d_in[1];
  const float* bq = (const float*)d_in[2];
  const float* Wk = (const float*)d_in[3];
  const float* bk = (const float*)d_in[4];
  const float* Wv = (const float*)d_in[5];
  const float* bv = (const float*)d_in[6];
  const float* Wo = (const float*)d_in[7];
  const float* bo = (const float*)d_in[8];
  float* out = (float*)d_out;

  // workspace layout (bytes): total 48 MiB
  char* ws = (char*)d_ws;
  u16* Xb  = (u16*)(ws);                    // 8 MiB  [4096,1024] bf16
  u16* Wt  = (u16*)(ws + (8u << 20));       // 8 MiB  4x [1024,1024] bf16 (transposed)
  u16* Qb  = (u16*)(ws + (16u << 20));      // 8 MiB  [B,H,S,DH]
  u16* Kb  = (u16*)(ws + (24u << 20));      // 8 MiB  [B,H,S,DH]
  u16* Vt  = (u16*)(ws + (32u << 20));      // 8 MiB  [B,H,DH,S]
  u16* Hh  = (u16*)(ws + (40u << 20));      // 8 MiB  [B,S,DM]
  (void)in_sizes; (void)n_in; (void)out_size; (void)ws_size;

  // 1) prep: x cvt + 4 weight transposes in one launch
  dim3 tp(32, 32, 5);
  prep_kernel<<<tp, 256, 0, stream>>>(x, Wq, Wk, Wv, Wo, Wt, Xb);
  // 2) fused QKV projection: 128x128, BK=32, XCD-banded -> 768 blocks
  dim3 gq(8, 32, 3);
  gemm_kernel<128, 128, 8><<<gq, 256, 0, stream>>>(Xb, Wt, bq, bk, bv, Qb, Kb, Vt, 0);
  // 3) causal flash attention -> Hh [B,S,DM] bf16 (4 heads per XCD)
  dim3 ga(16, 32);
  attn_kernel<<<ga, 256, 0, stream>>>(Qb, Kb, Vt, Hh);
  // 4) output projection: 128x64, BK=32, XCD-banded -> 512 blocks
  dim3 go(16, 32, 1);
  gemm_kernel<128, 64, 16><<<go, 256, 0, stream>>>(Hh, Wt + (3u << 20), bo, bo, bo, out, out, out, 3);
}

// Round 11
// 192.057 us; speedup vs baseline: 1.1144x; 1.0119x over previous
//
#include <hip/hip_runtime.h>

typedef unsigned short u16;
typedef unsigned int u32;
typedef __attribute__((ext_vector_type(8))) __bf16 bf16x8;
typedef __attribute__((ext_vector_type(4))) float f32x4;
typedef __attribute__((ext_vector_type(4))) unsigned short u16x4;
typedef __attribute__((ext_vector_type(2))) unsigned int u32x2;

#define SEQ 2048
#define DM 1024
#define NH 16
#define DH 64
// M = BATCH*SEQ = 4096, N = 1024, K = 1024 for all GEMMs

__device__ __forceinline__ float fexp2(float x) {
  return __builtin_amdgcn_exp2f(x); // raw v_exp_f32 (2^x)
}

__device__ __forceinline__ unsigned short f2bf(float f) {
  unsigned u = __builtin_bit_cast(unsigned, f);
  u += 0x7fffu + ((u >> 16) & 1u);
  return (unsigned short)(u >> 16);
}

__device__ __forceinline__ u32 cvtpk(float lo, float hi) { // {bf16(lo), bf16(hi)}
  u32 r;
  asm("v_cvt_pk_bf16_f32 %0, %1, %2" : "=v"(r) : "v"(lo), "v"(hi));
  return r;
}

__device__ __forceinline__ void gload_lds16(const u16* g, u16* l) {
  __builtin_amdgcn_global_load_lds(
      (const __attribute__((address_space(1))) u16*)g,
      (__attribute__((address_space(3))) u16*)l, 16, 0, 0);
}

// ---------- prep: weights transpose+cvt (z<4) and x cvt (z==4) ----------
__global__ __launch_bounds__(256) void prep_kernel(const float* __restrict__ x,
                                                   const float* __restrict__ W0,
                                                   const float* __restrict__ W1,
                                                   const float* __restrict__ W2,
                                                   const float* __restrict__ W3,
                                                   u16* __restrict__ WtBase,
                                                   u16* __restrict__ Xb) {
  if (blockIdx.z == 4) { // cvt x: 1024 blocks x 256 thr x 4 float4
    const int id = (blockIdx.y * 32 + blockIdx.x) * 256 + threadIdx.x;
#pragma unroll
    for (int rep = 0; rep < 4; ++rep) {
      const int idx = rep * 262144 + id;
      float4 v = ((const float4*)x)[idx];
      u16x4 o = { f2bf(v.x), f2bf(v.y), f2bf(v.z), f2bf(v.w) };
      ((u16x4*)Xb)[idx] = o;
    }
    return;
  }
  const float* W = (blockIdx.z == 0) ? W0 : (blockIdx.z == 1) ? W1
                 : (blockIdx.z == 2) ? W2 : W3;
  u16* Wt = WtBase + ((size_t)blockIdx.z << 20);
  __shared__ float tile[32][33];
  int tx = threadIdx.x & 31, ty = threadIdx.x >> 5; // 32 x 8
  int k0 = blockIdx.y * 32, n0 = blockIdx.x * 32;
#pragma unroll
  for (int j = 0; j < 32; j += 8)
    tile[ty + j][tx] = W[(size_t)(k0 + ty + j) * DM + n0 + tx];
  __syncthreads();
#pragma unroll
  for (int j = 0; j < 32; j += 8)
    Wt[(size_t)(n0 + ty + j) * DM + k0 + tx] = f2bf(tile[tx][ty + j]);
}

// ---------- GEMM v5: BK=32 swizzled + XCD-aware block remap ----------
// modes: 0=Q -> [B,H,S,DH] bf16 *0.125*log2e; 1=K; 2=V -> [B,H,DH,S]; 3=O fp32
template <int BM, int BN, int GX>
__global__ __launch_bounds__(256, 4) void gemm_kernel(
    const u16* __restrict__ A, const u16* __restrict__ WtBase,
    const float* __restrict__ b0, const float* __restrict__ b1,
    const float* __restrict__ b2,
    void* __restrict__ O0, void* __restrict__ O1, void* __restrict__ O2,
    int modeBase) {
  constexpr int MR = BM / 32, NR = BN / 32; // fragments per wave (2x2 wave grid)
  const int Kd = 1024, Nd = 1024;
  // XCD-aware bijective remap: rawid%8 = XCD (round-robin dispatch)
  const int rawid = (blockIdx.z * 32 + blockIdx.y) * GX + blockIdx.x;
  const int xcd = rawid & 7, slot = rawid >> 3;
  const int iy = xcd * 4 + (slot & 3);
  const int ix = (slot >> 2) % GX;
  const int iz = slot / (4 * GX);

  const int mode = modeBase + iz;
  const u16* Bt = WtBase + ((size_t)iz << 20);
  const float* bias = (iz == 0) ? b0 : (iz == 1) ? b1 : b2;
  void* Out = (iz == 0) ? O0 : (iz == 1) ? O1 : O2;

  __shared__ u16 As[2][BM * 32];
  __shared__ u16 Bs[2][BN * 32];
  const int tid = threadIdx.x;
  const int lane = tid & 63, w = tid >> 6;
  const int lrow = lane & 15, u = lane >> 4;
  const int wr = w >> 1, wc = w & 1;
  const int brow = iy * BM, bcol = ix * BN;

  f32x4 acc[MR][NR] = {};

  // staged via pre-swizzled per-lane global source; LDS dest linear (tid*16)
  auto stage = [&](int kt, int buf) {
#pragma unroll
    for (int i = 0; i < BM / 64; ++i) {
      const int p = i * 4096 + tid * 16;        // linear phys byte
      const int row = p >> 6;                   // 64B rows
      const int chunk = ((p >> 4) & 3) ^ (row & 3);
      gload_lds16(A + (size_t)(brow + row) * Kd + kt + chunk * 8, As[buf] + (p >> 1));
    }
#pragma unroll
    for (int i = 0; i < BN / 64; ++i) {
      const int p = i * 4096 + tid * 16;
      const int row = p >> 6;
      const int chunk = ((p >> 4) & 3) ^ (row & 3);
      gload_lds16(Bt + (size_t)(bcol + row) * Kd + kt + chunk * 8, Bs[buf] + (p >> 1));
    }
  };

  stage(0, 0);
  __syncthreads();

  for (int it = 0; it < 32; ++it) {
    const int cur = it & 1;
    if (it + 1 < 32) stage((it + 1) * 32, cur ^ 1); // prefetch overlaps compute
    bf16x8 af[MR], bfr[NR];
#pragma unroll
    for (int m = 0; m < MR; ++m) {
      const int r = wr * (BM / 2) + m * 16 + lrow;
      af[m] = *(const bf16x8*)(As[cur] + ((r * 64 + ((u * 16) ^ ((r & 3) << 4))) >> 1));
    }
#pragma unroll
    for (int n = 0; n < NR; ++n) {
      const int r = wc * (BN / 2) + n * 16 + lrow;
      bfr[n] = *(const bf16x8*)(Bs[cur] + ((r * 64 + ((u * 16) ^ ((r & 3) << 4))) >> 1));
    }
#pragma unroll
    for (int m = 0; m < MR; ++m)
#pragma unroll
      for (int n = 0; n < NR; ++n)
        acc[m][n] = __builtin_amdgcn_mfma_f32_16x16x32_bf16(af[m], bfr[n], acc[m][n], 0, 0, 0);
    __syncthreads();
  }

  const int r0 = brow + wr * (BM / 2) + u * 4; // + m*16 + i
  const int c0 = bcol + wc * (BN / 2) + lrow;  // + n*16
#pragma unroll
  for (int m = 0; m < MR; ++m) {
#pragma unroll
    for (int n = 0; n < NR; ++n) {
      const int col = c0 + n * 16;
      const float bv = bias[col];
      if (mode == 3) {
        float* O = (float*)Out;
#pragma unroll
        for (int i = 0; i < 4; ++i) {
          int row = r0 + m * 16 + i;
          O[(size_t)row * Nd + col] = acc[m][n][i] + bv;
        }
      } else if (mode == 2) {
        // V transposed: Vt[((b*16+h)*64+dh)*2048 + s], 4 consecutive s per thread
        const int rowb = r0 + m * 16;
        const int b = rowb >> 11, s = rowb & 2047;
        const int h = col >> 6, dh = col & 63;
        u16x4 pk;
#pragma unroll
        for (int i = 0; i < 4; ++i) pk[i] = f2bf(acc[m][n][i] + bv);
        u16* O = (u16*)Out;
        *(u16x4*)(O + ((size_t)((b * NH + h) * DH + dh) * SEQ + s)) = pk;
      } else {
        const float sc = (mode == 0) ? 0.1803368801111204f : 1.0f; // 0.125*log2e
        u16* O = (u16*)Out;
#pragma unroll
        for (int i = 0; i < 4; ++i) {
          int row = r0 + m * 16 + i;
          int b = row >> 11, s = row & 2047;
          int h = col >> 6, dh = col & 63;
          O[((size_t)(b * NH + h) * SEQ + s) * DH + dh] = f2bf((acc[m][n][i] + bv) * sc);
        }
      }
    }
  }
}

// ---------- causal flash attention, v7 ----------
// R7-proven compute path (shfl_xor softmax, LDS P round-trip) + KVBLK=128:
// two 64-kv subtiles per staged tile -> barriers 33 -> 17.
__device__ __forceinline__ void softmax_update(f32x4 (&s)[4], f32x4 (&hacc)[4],
                                               float& m_i, float& l_i) {
  float pg0 = fmaxf(fmaxf(s[0][0], s[0][1]), fmaxf(s[0][2], s[0][3]));
  float pg1 = fmaxf(fmaxf(s[1][0], s[1][1]), fmaxf(s[1][2], s[1][3]));
  float pg2 = fmaxf(fmaxf(s[2][0], s[2][1]), fmaxf(s[2][2], s[2][3]));
  float pg3 = fmaxf(fmaxf(s[3][0], s[3][1]), fmaxf(s[3][2], s[3][3]));
  float pmax = fmaxf(fmaxf(pg0, pg1), fmaxf(pg2, pg3));
  pmax = fmaxf(pmax, __shfl_xor(pmax, 16));
  pmax = fmaxf(pmax, __shfl_xor(pmax, 32));
  if (__any(pmax > m_i + 8.0f)) { // defer-max: P bounded by 2^8, bf16-safe
    const float mnew = fmaxf(m_i, pmax);
    const float scl = fexp2(m_i - mnew);
    l_i *= scl;
#pragma unroll
    for (int g = 0; g < 4; ++g) hacc[g] *= scl;
    m_i = mnew;
  }
  float rs = 0.f;
#pragma unroll
  for (int g = 0; g < 4; ++g)
#pragma unroll
    for (int i = 0; i < 4; ++i) {
      const float p = fexp2(s[g][i] - m_i);
      s[g][i] = p;
      rs += p;
    }
  rs += __shfl_xor(rs, 16);
  rs += __shfl_xor(rs, 32);
  l_i += rs;
}

__device__ __forceinline__ void write_p(u16* ps, const f32x4 (&s)[4], int lrow, int u) {
#pragma unroll
  for (int g = 0; g < 4; ++g) {
    u32x2 pw = { cvtpk(s[g][0], s[g][1]), cvtpk(s[g][2], s[g][3]) };
    *(u32x2*)(ps + ((lrow * 128 + ((g * 32 + u * 8) ^ ((lrow & 7) << 4))) >> 1)) = pw;
  }
}

__global__ __launch_bounds__(256, 2) void attn_kernel(const u16* __restrict__ Qb,
                                                      const u16* __restrict__ Kb,
                                                      const u16* __restrict__ Vt,
                                                      u16* __restrict__ Hh) {
  // XCD-aware remap: 4 heads per XCD, 16 q-pair blocks per head co-located
  const int rawid = blockIdx.y * 16 + blockIdx.x;
  const int xcd = rawid & 7, slot = rawid >> 3;
  const int bh = xcd * 4 + (slot >> 4);
  const int px = slot & 15;
  const int qtA = px, qtB = 31 - px;
  const int tid = threadIdx.x, lane = tid & 63, w = tid >> 6;
  const int lrow = lane & 15, u = lane >> 4;

  const u16* Qp = Qb + (size_t)bh * SEQ * DH;
  const u16* Kp = Kb + (size_t)bh * SEQ * DH;
  const u16* Vp = Vt + (size_t)bh * DH * SEQ;

  __shared__ u16 KV[2][2][2][4096]; // [buf][K/V][sub][64x64 swizzled] = 64KB
  __shared__ u16 Ps[4][2][1024];    // [wave][stream][16x64], swizzled

  const int q0A = qtA * 64 + w * 16, q0B = qtB * 64 + w * 16;
  bf16x8 qfA[2], qfB[2];
#pragma unroll
  for (int ks = 0; ks < 2; ++ks) {
    qfA[ks] = *(const bf16x8*)(Qp + (size_t)(q0A + lrow) * DH + ks * 32 + u * 8);
    qfB[ks] = *(const bf16x8*)(Qp + (size_t)(q0B + lrow) * DH + ks * 32 + u * 8);
  }

  float mA = -1e30f, lA = 0.f, mB = -1e30f, lB = 0.f;
  f32x4 haccA[4], haccB[4];
#pragma unroll
  for (int g = 0; g < 4; ++g) {
    haccA[g] = (f32x4){0.f, 0.f, 0.f, 0.f};
    haccB[g] = (f32x4){0.f, 0.f, 0.f, 0.f};
  }

  // stage one 128-kv tile (K 16KB + V 16KB) as 2 sub-tiles of [64][64]
  auto stage = [&](int kt, int buf) {
#pragma unroll
    for (int s = 0; s < 2; ++s)
#pragma unroll
      for (int i = 0; i < 2; ++i) {
        const int p = i * 4096 + tid * 16;          // phys byte in 8KB sub
        const int row = p >> 7;                     // 128B rows
        const int c16 = ((p >> 4) & 7) ^ (row & 7); // pre-swizzled source col
        gload_lds16(Kp + (size_t)(kt * 128 + s * 64 + row) * 64 + c16 * 8,
                    &KV[buf][0][s][p >> 1]);
        gload_lds16(Vp + (size_t)row * 2048 + kt * 128 + s * 64 + c16 * 8,
                    &KV[buf][1][s][p >> 1]);
      }
  };

  stage(0, 0);
  __syncthreads();

  const int wq = w * 16 + lrow;
  const int nkt = (qtB + 2) >> 1; // ceil((qtB+1)/2) 128-kv tiles
  for (int kt = 0; kt < nkt; ++kt) {
    const int cur = kt & 1;
    if (kt + 1 < nkt) stage(kt + 1, cur ^ 1); // prefetch overlaps compute
#pragma unroll
    for (int sub = 0; sub < 2; ++sub) {
      const int kvt = 2 * kt + sub; // 64-kv tile index
      if (kvt > qtB) continue;
      const u16* bufK = &KV[cur][0][sub][0];
      const u16* bufV = &KV[cur][1][sub][0];
      const bool doA = (kvt <= qtA);

      // --- K fragments, shared by both streams ---
      bf16x8 kf[2][4];
#pragma unroll
      for (int ks = 0; ks < 2; ++ks) {
        const int c = ks * 64 + u * 16;
#pragma unroll
        for (int g = 0; g < 4; ++g) {
          const int r = g * 16 + lrow;
          kf[ks][g] = *(const bf16x8*)(bufK + ((r * 128 + (c ^ ((r & 7) << 4))) >> 1));
        }
      }
      // --- QK^T both streams ---
      f32x4 sA[4] = {}, sB[4] = {};
      __builtin_amdgcn_s_setprio(1);
#pragma unroll
      for (int ks = 0; ks < 2; ++ks)
#pragma unroll
        for (int g = 0; g < 4; ++g)
          sB[g] = __builtin_amdgcn_mfma_f32_16x16x32_bf16(kf[ks][g], qfB[ks], sB[g], 0, 0, 0);
      if (doA) {
#pragma unroll
        for (int ks = 0; ks < 2; ++ks)
#pragma unroll
          for (int g = 0; g < 4; ++g)
            sA[g] = __builtin_amdgcn_mfma_f32_16x16x32_bf16(kf[ks][g], qfA[ks], sA[g], 0, 0, 0);
      }
      __builtin_amdgcn_s_setprio(0);
      // --- masks + softmax + P writes (LDS, proven path) ---
      if (kvt == qtB) {
#pragma unroll
        for (int g = 0; g < 4; ++g) {
          const int kb = g * 16 + u * 4;
#pragma unroll
          for (int i = 0; i < 4; ++i)
            if (kb + i > wq) sB[g][i] = -1e30f;
        }
      }
      softmax_update(sB, haccB, mB, lB);
      write_p(&Ps[w][1][0], sB, lrow, u);
      if (doA) {
        if (kvt == qtA) {
#pragma unroll
          for (int g = 0; g < 4; ++g) {
            const int kb = g * 16 + u * 4;
#pragma unroll
            for (int i = 0; i < 4; ++i)
              if (kb + i > wq) sA[g][i] = -1e30f;
          }
        }
        softmax_update(sA, haccA, mA, lA);
        write_p(&Ps[w][0][0], sA, lrow, u);
      }
      // --- V fragments (shared) + P fragments ---
      bf16x8 vf[2][4], pfB[2], pfA[2];
#pragma unroll
      for (int ks = 0; ks < 2; ++ks) {
        const int c = ks * 64 + u * 16;
#pragma unroll
        for (int g = 0; g < 4; ++g) {
          const int r = g * 16 + lrow;
          vf[ks][g] = *(const bf16x8*)(bufV + ((r * 128 + (c ^ ((r & 7) << 4))) >> 1));
        }
        pfB[ks] = *(const bf16x8*)(&Ps[w][1][0] + ((lrow * 128 + (c ^ ((lrow & 7) << 4))) >> 1));
        if (doA)
          pfA[ks] = *(const bf16x8*)(&Ps[w][0][0] + ((lrow * 128 + (c ^ ((lrow & 7) << 4))) >> 1));
      }
      // --- PV both streams ---
      __builtin_amdgcn_s_setprio(1);
#pragma unroll
      for (int ks = 0; ks < 2; ++ks)
#pragma unroll
        for (int g = 0; g < 4; ++g)
          haccB[g] = __builtin_amdgcn_mfma_f32_16x16x32_bf16(vf[ks][g], pfB[ks], haccB[g], 0, 0, 0);
      if (doA) {
#pragma unroll
        for (int ks = 0; ks < 2; ++ks)
#pragma unroll
          for (int g = 0; g < 4; ++g)
            haccA[g] = __builtin_amdgcn_mfma_f32_16x16x32_bf16(vf[ks][g], pfA[ks], haccA[g], 0, 0, 0);
      }
      __builtin_amdgcn_s_setprio(0);
    }
    __syncthreads(); // prefetch landed + everyone done with cur
  }

  const int b = bh >> 4, h = bh & 15;
  {
    const float inv = 1.0f / lA;
    u16* dst = Hh + ((size_t)b * SEQ + (q0A + lrow)) * DM + h * DH + u * 4;
#pragma unroll
    for (int g = 0; g < 4; ++g) {
      u32x2 pk = { cvtpk(haccA[g][0] * inv, haccA[g][1] * inv),
                   cvtpk(haccA[g][2] * inv, haccA[g][3] * inv) };
      *(u32x2*)(dst + g * 16) = pk;
    }
  }
  {
    const float inv = 1.0f / lB;
    u16* dst = Hh + ((size_t)b * SEQ + (q0B + lrow)) * DM + h * DH + u * 4;
#pragma unroll
    for (int g = 0; g < 4; ++g) {
      u32x2 pk = { cvtpk(haccB[g][0] * inv, haccB[g][1] * inv),
                   cvtpk(haccB[g][2] * inv, haccB[g][3] * inv) };
      *(u32x2*)(dst + g * 16) = pk;
    }
  }
}

extern "C" void kernel_launch(void* const* d_in, const int* in_sizes, int n_in,
                              void* d_out, int out_size, void* d_ws, size_t ws_size,
                              hipStream_t stream) {
  const float* x  = (const float*)d_in[0];
  const float* Wq = (const float*)d_in[1];
  const float* bq = (const float*)d_in[2];
  const float* Wk = (const float*)d_in[3];
  const float* bk = (const float*)d_in[4];
  const float* Wv = (const float*)d_in[5];
  const float* bv = (const float*)d_in[6];
  const float* Wo = (const float*)d_in[7];
  const float* bo = (const float*)d_in[8];
  float* out = (float*)d_out;

  // workspace layout (bytes): total 48 MiB
  char* ws = (char*)d_ws;
  u16* Xb  = (u16*)(ws);                    // 8 MiB  [4096,1024] bf16
  u16* Wt  = (u16*)(ws + (8u << 20));       // 8 MiB  4x [1024,1024] bf16 (transposed)
  u16* Qb  = (u16*)(ws + (16u << 20));      // 8 MiB  [B,H,S,DH]
  u16* Kb  = (u16*)(ws + (24u << 20));      // 8 MiB  [B,H,S,DH]
  u16* Vt  = (u16*)(ws + (32u << 20));      // 8 MiB  [B,H,DH,S]
  u16* Hh  = (u16*)(ws + (40u << 20));      // 8 MiB  [B,S,DM]
  (void)in_sizes; (void)n_in; (void)out_size; (void)ws_size;

  // 1) prep: x cvt + 4 weight transposes in one launch
  dim3 tp(32, 32, 5);
  prep_kernel<<<tp, 256, 0, stream>>>(x, Wq, Wk, Wv, Wo, Wt, Xb);
  // 2) fused QKV projection: 128x128, BK=32, XCD-banded -> 768 blocks
  dim3 gq(8, 32, 3);
  gemm_kernel<128, 128, 8><<<gq, 256, 0, stream>>>(Xb, Wt, bq, bk, bv, Qb, Kb, Vt, 0);
  // 3) causal flash attention -> Hh [B,S,DM] bf16 (4 heads per XCD)
  dim3 ga(16, 32);
  attn_kernel<<<ga, 256, 0, stream>>>(Qb, Kb, Vt, Hh);
  // 4) output projection: 128x64, BK=32, XCD-banded -> 512 blocks
  dim3 go(16, 32, 1);
  gemm_kernel<128, 64, 16><<<go, 256, 0, stream>>>(Hh, Wt + (3u << 20), bo, bo, bo, out, out, out, 3);
}